// Round 3
// baseline (433.691 us; speedup 1.0000x reference)
//
#include <hip/hip_runtime.h>
#include <cmath>

#define NPTS 1048576
#define TABLE_SZ 524288

typedef _Float16 half8 __attribute__((ext_vector_type(8)));
typedef _Float16 half4 __attribute__((ext_vector_type(4)));
typedef float floatx4 __attribute__((ext_vector_type(4)));
typedef float float4a8 __attribute__((ext_vector_type(4), aligned(8)));

#define MFMA16x16x32 __builtin_amdgcn_mfma_f32_16x16x32_f16

// ---------------------------------------------------------------------------
// Pre-pack all MLP weights into f16 MFMA A-fragments (W^T as A operand).
//   lane l holds row m = l&15, k = 32*kt + (l>>4)*8 + e, e in [0,8).
// Frag table (20 frags, 1 KB each):
//   [0,4) ws0 | [4,6) ws1 | [6,10) wc0 (k=31 pad) | [10,18) wc1 | [18,20) wc2
// ---------------------------------------------------------------------------
__global__ void prepack_weights(const float* __restrict__ ws0,
                                const float* __restrict__ ws1,
                                const float* __restrict__ wc0,
                                const float* __restrict__ wc1,
                                const float* __restrict__ wc2,
                                half8* __restrict__ wfrag)
{
    const int f = blockIdx.x, l = threadIdx.x;
    const float* W; int Kreal, Mreal, mt, kt;
    if (f < 4)       { W = ws0; Kreal = 32; Mreal = 64; mt = f;          kt = 0;        }
    else if (f < 6)  { W = ws1; Kreal = 64; Mreal = 16; mt = 0;          kt = f - 4;    }
    else if (f < 10) { W = wc0; Kreal = 31; Mreal = 64; mt = f - 6;      kt = 0;        }
    else if (f < 18) { W = wc1; Kreal = 64; Mreal = 64; mt = (f-10)>>1;  kt = (f-10)&1; }
    else             { W = wc2; Kreal = 64; Mreal = 1;  mt = 0;          kt = f - 18;   }

    const int m  = 16*mt + (l & 15);
    const int k0 = 32*kt + (l >> 4)*8;
    half8 hv;
    #pragma unroll
    for (int e = 0; e < 8; ++e) {
        const int k = k0 + e;
        const float v = (m < Mreal && k < Kreal) ? W[k*Mreal + m] : 0.0f;
        hv[e] = (_Float16)v;
    }
    wfrag[f*64 + l] = hv;
}

// ---------------------------------------------------------------------------
// Gather kernel: 4 threads/point, 4 levels/thread, no LDS, low VGPR.
// Corner x-pairs loaded as one 16B float4 (8B-aligned). Output: f16 feats
// [NPTS][32], thread writes one 16B chunk -> wave writes 1KB contiguous.
// ---------------------------------------------------------------------------
__global__ __launch_bounds__(256) void ngp_gather(
    const float* __restrict__ xin, const float* __restrict__ emb,
    _Float16* __restrict__ feats,
    int4 ra, int4 rb, int4 rc, int4 rd)
{
    const int tid = blockIdx.x * 256 + threadIdx.x;
    const int p = tid >> 2;            // point
    const int q = tid & 3;             // level quad: levels 4q..4q+3

    const float px = (xin[3*p+0] + 1.0f) * 0.5f;
    const float py = (xin[3*p+1] + 1.0f) * 0.5f;
    const float pz = (xin[3*p+2] + 1.0f) * 0.5f;

    const int4 rv = (q == 0) ? ra : (q == 1) ? rb : (q == 2) ? rc : rd;

    half8 hv;
    #pragma unroll
    for (int j = 0; j < 4; ++j) {
        const int R = (j == 0) ? rv.x : (j == 1) ? rv.y : (j == 2) ? rv.z : rv.w;
        const int lv = 4*q + j;
        const float Rf = (float)R;
        const float gx = px*Rf, gy = py*Rf, gz = pz*Rf;
        int x0 = (int)floorf(gx); x0 = x0 < 0 ? 0 : (x0 > R-1 ? R-1 : x0);
        int y0 = (int)floorf(gy); y0 = y0 < 0 ? 0 : (y0 > R-1 ? R-1 : y0);
        int z0 = (int)floorf(gz); z0 = z0 < 0 ? 0 : (z0 > R-1 ? R-1 : z0);
        const float fx = gx - (float)x0, fy = gy - (float)y0, fz = gz - (float)z0;
        const int s1 = R + 1, s2 = s1 * s1;
        const float* tab = emb + (size_t)lv * (size_t)(TABLE_SZ * 2);
        const int b = x0 + y0*s1 + z0*s2;
        // each float4 = corners (x0, x0+1) at one (y,z): [c0.x c0.y c1.x c1.y]
        const float4a8 P00 = *(const float4a8*)(tab + 2*(b));
        const float4a8 P10 = *(const float4a8*)(tab + 2*(b + s1));
        const float4a8 P01 = *(const float4a8*)(tab + 2*(b + s2));
        const float4a8 P11 = *(const float4a8*)(tab + 2*(b + s1 + s2));
        // lerp x
        const float a00x = fmaf(fx, P00.z - P00.x, P00.x);
        const float a00y = fmaf(fx, P00.w - P00.y, P00.y);
        const float a10x = fmaf(fx, P10.z - P10.x, P10.x);
        const float a10y = fmaf(fx, P10.w - P10.y, P10.y);
        const float a01x = fmaf(fx, P01.z - P01.x, P01.x);
        const float a01y = fmaf(fx, P01.w - P01.y, P01.y);
        const float a11x = fmaf(fx, P11.z - P11.x, P11.x);
        const float a11y = fmaf(fx, P11.w - P11.y, P11.y);
        // lerp y
        const float b0x = fmaf(fy, a10x - a00x, a00x);
        const float b1x = fmaf(fy, a11x - a01x, a01x);
        const float b0y = fmaf(fy, a10y - a00y, a00y);
        const float b1y = fmaf(fy, a11y - a01y, a01y);
        // lerp z
        hv[2*j+0] = (_Float16)fmaf(fz, b1x - b0x, b0x);
        hv[2*j+1] = (_Float16)fmaf(fz, b1y - b0y, b0y);
    }
    *(half8*)&feats[(size_t)p*32 + q*8] = hv;
}

// ---------------------------------------------------------------------------
// MLP kernel. 4 waves/block, 32 points/wave (wave-private LDS, no
// __syncthreads). Layers computed as Y^T = W^T @ X^T: points ride the
// B/N operand (col = lane&15), features the M operand.
// ---------------------------------------------------------------------------
__global__ __launch_bounds__(256) void ngp_mlp(
    const float* __restrict__ din, const _Float16* __restrict__ feats,
    const half8* __restrict__ wfrag, float* __restrict__ out)
{
    __shared__ __align__(16) _Float16 smM[4][32][72];  // H / c1 / c2
    __shared__ __align__(16) _Float16 smG[4][32][24];  // geo feats (hd 16-31)

    const int tid  = threadIdx.x;
    const int w    = tid >> 6, lane = tid & 63;
    const int gbase = (blockIdx.x * 4 + w) * 32;

    const int n = lane & 15, g = lane >> 4;
    const floatx4 zz = {0.f, 0.f, 0.f, 0.f};

    auto storeQ = [&](int pt, int mt, floatx4 a) {  // relu + f16, cols [16mt+4g, +4)
        half4 hv;
        hv[0] = (_Float16)fmaxf(a[0], 0.f); hv[1] = (_Float16)fmaxf(a[1], 0.f);
        hv[2] = (_Float16)fmaxf(a[2], 0.f); hv[3] = (_Float16)fmaxf(a[3], 0.f);
        *(half4*)&smM[w][pt][16*mt + 4*g] = hv;
    };

    // ================= S0: feats[32] @ ws0 -> H[64], relu  (B from global)
    {
        const half8 A0 = wfrag[0*64+lane], A1 = wfrag[1*64+lane];
        const half8 A2 = wfrag[2*64+lane], A3 = wfrag[3*64+lane];
        #pragma unroll
        for (int nt = 0; nt < 2; ++nt) {
            const int pt = nt*16 + n;
            const half8 B = *(const half8*)&feats[(size_t)(gbase + pt)*32 + 8*g];
            floatx4 a0 = MFMA16x16x32(A0, B, zz, 0,0,0);
            floatx4 a1 = MFMA16x16x32(A1, B, zz, 0,0,0);
            floatx4 a2 = MFMA16x16x32(A2, B, zz, 0,0,0);
            floatx4 a3 = MFMA16x16x32(A3, B, zz, 0,0,0);
            storeQ(pt, 0, a0); storeQ(pt, 1, a1); storeQ(pt, 2, a2); storeQ(pt, 3, a3);
        }
    }
    asm volatile("" ::: "memory");

    // ================= S1: H[64] @ ws1 -> G[16] (linear); sigma + geo out
    {
        const half8 A0 = wfrag[4*64+lane], A1 = wfrag[5*64+lane];
        #pragma unroll
        for (int nt = 0; nt < 2; ++nt) {
            const int pt = nt*16 + n;
            const half8 B0 = *(const half8*)&smM[w][pt][ 0 + 8*g];
            const half8 B1 = *(const half8*)&smM[w][pt][32 + 8*g];
            floatx4 acc = MFMA16x16x32(A0, B0, zz, 0,0,0);
            acc = MFMA16x16x32(A1, B1, acc, 0,0,0);
            if (g == 0) {
                out[gbase + pt] = fabsf(acc[0]);             // sigma = |g0|
                smG[w][pt][0]  = (_Float16)acc[1];
                smG[w][pt][1]  = (_Float16)acc[2];
                smG[w][pt][2]  = (_Float16)acc[3];
                smG[w][pt][15] = (_Float16)0.f;              // hd[31] pad
            } else {
                smG[w][pt][4*g-1] = (_Float16)acc[0];
                smG[w][pt][4*g+0] = (_Float16)acc[1];
                smG[w][pt][4*g+1] = (_Float16)acc[2];
                smG[w][pt][4*g+2] = (_Float16)acc[3];
            }
        }
    }
    asm volatile("" ::: "memory");

    // ================= C0: hd[32] @ wc0 -> c1[64], relu
    {
        const half8 A0 = wfrag[6*64+lane], A1 = wfrag[7*64+lane];
        const half8 A2 = wfrag[8*64+lane], A3 = wfrag[9*64+lane];
        #pragma unroll
        for (int nt = 0; nt < 2; ++nt) {
            const int pt = nt*16 + n;
            half8 B;
            if (g < 2) {
                const int gpt = gbase + pt;
                const float x = din[3*gpt+0], y = din[3*gpt+1], z = din[3*gpt+2];
                const float xx = x*x, yy = y*y, zzq = z*z;
                const float xy = x*y, yz = y*z, xz = x*z;
                float s[8];
                if (g == 0) {
                    s[0] = 0.28209479177387814f;
                    s[1] = -0.48860251190291987f * y;
                    s[2] =  0.48860251190291987f * z;
                    s[3] = -0.48860251190291987f * x;
                    s[4] =  1.0925484305920792f * xy;
                    s[5] = -1.0925484305920792f * yz;
                    s[6] =  0.94617469575756f * zzq - 0.31539156525252005f;
                    s[7] = -1.0925484305920792f * xz;
                } else {
                    s[0] =  0.5462742152960396f * (xx - yy);
                    s[1] =  0.5900435899266435f * y * (yy - 3.0f*xx);
                    s[2] =  2.890611442640554f * xy * z;
                    s[3] =  0.4570457994644657f * y * (1.0f - 5.0f*zzq);
                    s[4] =  0.3731763325901154f * z * (5.0f*zzq - 3.0f);
                    s[5] =  0.4570457994644657f * x * (1.0f - 5.0f*zzq);
                    s[6] =  1.445305721320277f * z * (xx - yy);
                    s[7] =  0.5900435899266435f * x * (3.0f*yy - xx);
                }
                #pragma unroll
                for (int e = 0; e < 8; ++e) B[e] = (_Float16)s[e];
            } else {
                B = *(const half8*)&smG[w][pt][8*(g-2)];
            }
            floatx4 a0 = MFMA16x16x32(A0, B, zz, 0,0,0);
            floatx4 a1 = MFMA16x16x32(A1, B, zz, 0,0,0);
            floatx4 a2 = MFMA16x16x32(A2, B, zz, 0,0,0);
            floatx4 a3 = MFMA16x16x32(A3, B, zz, 0,0,0);
            storeQ(pt, 0, a0); storeQ(pt, 1, a1); storeQ(pt, 2, a2); storeQ(pt, 3, a3);
        }
    }
    asm volatile("" ::: "memory");

    // ================= C1: c1[64] @ wc1 -> c2[64], relu
    {
        const half8 A0 = wfrag[10*64+lane], A1 = wfrag[11*64+lane];
        const half8 A2 = wfrag[12*64+lane], A3 = wfrag[13*64+lane];
        const half8 A4 = wfrag[14*64+lane], A5 = wfrag[15*64+lane];
        const half8 A6 = wfrag[16*64+lane], A7 = wfrag[17*64+lane];
        #pragma unroll
        for (int nt = 0; nt < 2; ++nt) {
            const int pt = nt*16 + n;
            const half8 B0 = *(const half8*)&smM[w][pt][ 0 + 8*g];
            const half8 B1 = *(const half8*)&smM[w][pt][32 + 8*g];
            floatx4 a0 = MFMA16x16x32(A0, B0, zz, 0,0,0); a0 = MFMA16x16x32(A1, B1, a0, 0,0,0);
            floatx4 a1 = MFMA16x16x32(A2, B0, zz, 0,0,0); a1 = MFMA16x16x32(A3, B1, a1, 0,0,0);
            floatx4 a2 = MFMA16x16x32(A4, B0, zz, 0,0,0); a2 = MFMA16x16x32(A5, B1, a2, 0,0,0);
            floatx4 a3 = MFMA16x16x32(A6, B0, zz, 0,0,0); a3 = MFMA16x16x32(A7, B1, a3, 0,0,0);
            storeQ(pt, 0, a0); storeQ(pt, 1, a1); storeQ(pt, 2, a2); storeQ(pt, 3, a3);
        }
    }
    asm volatile("" ::: "memory");

    // ================= C2: c2[64] @ wc2 -> color (|.|)
    {
        const half8 A0 = wfrag[18*64+lane], A1 = wfrag[19*64+lane];
        #pragma unroll
        for (int nt = 0; nt < 2; ++nt) {
            const int pt = nt*16 + n;
            const half8 B0 = *(const half8*)&smM[w][pt][ 0 + 8*g];
            const half8 B1 = *(const half8*)&smM[w][pt][32 + 8*g];
            floatx4 acc = MFMA16x16x32(A0, B0, zz, 0,0,0);
            acc = MFMA16x16x32(A1, B1, acc, 0,0,0);
            if (g == 0) out[NPTS + gbase + pt] = fabsf(acc[0]);
        }
    }
}

// ---------------------------------------------------------------------------
// Fallback fused kernel (round-2 structure) for small ws_size.
// ---------------------------------------------------------------------------
__global__ __launch_bounds__(256) void ngp_fused_fb(
    const float* __restrict__ xin, const float* __restrict__ din,
    const float* __restrict__ emb, const half8* __restrict__ wfrag,
    float* __restrict__ out, int4 ra, int4 rb, int4 rc, int4 rd)
{
    __shared__ __align__(16) _Float16 smM[4][32][72];
    __shared__ __align__(16) _Float16 smG[4][32][24];
    const int tid  = threadIdx.x;
    const int w    = tid >> 6, lane = tid & 63;
    const int gbase = (blockIdx.x * 4 + w) * 32;
    {
        const int p  = lane & 31, hi = lane >> 5;
        const int gpt = gbase + p;
        const float px = (xin[3*gpt+0] + 1.0f) * 0.5f;
        const float py = (xin[3*gpt+1] + 1.0f) * 0.5f;
        const float pz = (xin[3*gpt+2] + 1.0f) * 0.5f;
        float ft[16];
        #pragma unroll
        for (int j = 0; j < 8; ++j) {
            int R;
            if      (j == 0) R = hi ? rc.x : ra.x;
            else if (j == 1) R = hi ? rc.y : ra.y;
            else if (j == 2) R = hi ? rc.z : ra.z;
            else if (j == 3) R = hi ? rc.w : ra.w;
            else if (j == 4) R = hi ? rd.x : rb.x;
            else if (j == 5) R = hi ? rd.y : rb.y;
            else if (j == 6) R = hi ? rd.z : rb.z;
            else             R = hi ? rd.w : rb.w;
            const int lv = hi*8 + j;
            const float Rf = (float)R;
            const float gx = px*Rf, gy = py*Rf, gz = pz*Rf;
            int x0 = (int)floorf(gx); x0 = x0 < 0 ? 0 : (x0 > R-1 ? R-1 : x0);
            int y0 = (int)floorf(gy); y0 = y0 < 0 ? 0 : (y0 > R-1 ? R-1 : y0);
            int z0 = (int)floorf(gz); z0 = z0 < 0 ? 0 : (z0 > R-1 ? R-1 : z0);
            const float fx = gx - (float)x0, fy = gy - (float)y0, fz = gz - (float)z0;
            const int s1 = R + 1, s2 = s1 * s1;
            const float* tab = emb + (size_t)lv * (size_t)(TABLE_SZ * 2);
            const int b = x0 + y0*s1 + z0*s2;
            const float4a8 P00 = *(const float4a8*)(tab + 2*(b));
            const float4a8 P10 = *(const float4a8*)(tab + 2*(b + s1));
            const float4a8 P01 = *(const float4a8*)(tab + 2*(b + s2));
            const float4a8 P11 = *(const float4a8*)(tab + 2*(b + s1 + s2));
            const float a00x = fmaf(fx, P00.z - P00.x, P00.x);
            const float a00y = fmaf(fx, P00.w - P00.y, P00.y);
            const float a10x = fmaf(fx, P10.z - P10.x, P10.x);
            const float a10y = fmaf(fx, P10.w - P10.y, P10.y);
            const float a01x = fmaf(fx, P01.z - P01.x, P01.x);
            const float a01y = fmaf(fx, P01.w - P01.y, P01.y);
            const float a11x = fmaf(fx, P11.z - P11.x, P11.x);
            const float a11y = fmaf(fx, P11.w - P11.y, P11.y);
            const float b0x = fmaf(fy, a10x - a00x, a00x);
            const float b1x = fmaf(fy, a11x - a01x, a01x);
            const float b0y = fmaf(fy, a10y - a00y, a00y);
            const float b1y = fmaf(fy, a11y - a01y, a01y);
            ft[2*j+0] = fmaf(fz, b1x - b0x, b0x);
            ft[2*j+1] = fmaf(fz, b1y - b0y, b0y);
        }
        half8 v0, v1;
        #pragma unroll
        for (int c = 0; c < 8; ++c) { v0[c] = (_Float16)ft[c]; v1[c] = (_Float16)ft[8+c]; }
        *(half8*)&smM[w][p][16*hi + 0] = v0;
        *(half8*)&smM[w][p][16*hi + 8] = v1;
    }
    asm volatile("" ::: "memory");
    const int n = lane & 15, g = lane >> 4;
    const floatx4 zz = {0.f, 0.f, 0.f, 0.f};
    auto storeQ = [&](int pt, int mt, floatx4 a) {
        half4 hv;
        hv[0] = (_Float16)fmaxf(a[0], 0.f); hv[1] = (_Float16)fmaxf(a[1], 0.f);
        hv[2] = (_Float16)fmaxf(a[2], 0.f); hv[3] = (_Float16)fmaxf(a[3], 0.f);
        *(half4*)&smM[w][pt][16*mt + 4*g] = hv;
    };
    {
        const half8 A0 = wfrag[0*64+lane], A1 = wfrag[1*64+lane];
        const half8 A2 = wfrag[2*64+lane], A3 = wfrag[3*64+lane];
        #pragma unroll
        for (int nt = 0; nt < 2; ++nt) {
            const int pt = nt*16 + n;
            const half8 B = *(const half8*)&smM[w][pt][8*g];
            floatx4 a0 = MFMA16x16x32(A0, B, zz, 0,0,0);
            floatx4 a1 = MFMA16x16x32(A1, B, zz, 0,0,0);
            floatx4 a2 = MFMA16x16x32(A2, B, zz, 0,0,0);
            floatx4 a3 = MFMA16x16x32(A3, B, zz, 0,0,0);
            storeQ(pt, 0, a0); storeQ(pt, 1, a1); storeQ(pt, 2, a2); storeQ(pt, 3, a3);
        }
    }
    asm volatile("" ::: "memory");
    {
        const half8 A0 = wfrag[4*64+lane], A1 = wfrag[5*64+lane];
        #pragma unroll
        for (int nt = 0; nt < 2; ++nt) {
            const int pt = nt*16 + n;
            const half8 B0 = *(const half8*)&smM[w][pt][ 0 + 8*g];
            const half8 B1 = *(const half8*)&smM[w][pt][32 + 8*g];
            floatx4 acc = MFMA16x16x32(A0, B0, zz, 0,0,0);
            acc = MFMA16x16x32(A1, B1, acc, 0,0,0);
            if (g == 0) {
                out[gbase + pt] = fabsf(acc[0]);
                smG[w][pt][0]  = (_Float16)acc[1];
                smG[w][pt][1]  = (_Float16)acc[2];
                smG[w][pt][2]  = (_Float16)acc[3];
                smG[w][pt][15] = (_Float16)0.f;
            } else {
                smG[w][pt][4*g-1] = (_Float16)acc[0];
                smG[w][pt][4*g+0] = (_Float16)acc[1];
                smG[w][pt][4*g+1] = (_Float16)acc[2];
                smG[w][pt][4*g+2] = (_Float16)acc[3];
            }
        }
    }
    asm volatile("" ::: "memory");
    {
        const half8 A0 = wfrag[6*64+lane], A1 = wfrag[7*64+lane];
        const half8 A2 = wfrag[8*64+lane], A3 = wfrag[9*64+lane];
        #pragma unroll
        for (int nt = 0; nt < 2; ++nt) {
            const int pt = nt*16 + n;
            half8 B;
            if (g < 2) {
                const int gpt = gbase + pt;
                const float x = din[3*gpt+0], y = din[3*gpt+1], z = din[3*gpt+2];
                const float xx = x*x, yy = y*y, zzq = z*z;
                const float xy = x*y, yz = y*z, xz = x*z;
                float s[8];
                if (g == 0) {
                    s[0] = 0.28209479177387814f;
                    s[1] = -0.48860251190291987f * y;
                    s[2] =  0.48860251190291987f * z;
                    s[3] = -0.48860251190291987f * x;
                    s[4] =  1.0925484305920792f * xy;
                    s[5] = -1.0925484305920792f * yz;
                    s[6] =  0.94617469575756f * zzq - 0.31539156525252005f;
                    s[7] = -1.0925484305920792f * xz;
                } else {
                    s[0] =  0.5462742152960396f * (xx - yy);
                    s[1] =  0.5900435899266435f * y * (yy - 3.0f*xx);
                    s[2] =  2.890611442640554f * xy * z;
                    s[3] =  0.4570457994644657f * y * (1.0f - 5.0f*zzq);
                    s[4] =  0.3731763325901154f * z * (5.0f*zzq - 3.0f);
                    s[5] =  0.4570457994644657f * x * (1.0f - 5.0f*zzq);
                    s[6] =  1.445305721320277f * z * (xx - yy);
                    s[7] =  0.5900435899266435f * x * (3.0f*yy - xx);
                }
                #pragma unroll
                for (int e = 0; e < 8; ++e) B[e] = (_Float16)s[e];
            } else {
                B = *(const half8*)&smG[w][pt][8*(g-2)];
            }
            floatx4 a0 = MFMA16x16x32(A0, B, zz, 0,0,0);
            floatx4 a1 = MFMA16x16x32(A1, B, zz, 0,0,0);
            floatx4 a2 = MFMA16x16x32(A2, B, zz, 0,0,0);
            floatx4 a3 = MFMA16x16x32(A3, B, zz, 0,0,0);
            storeQ(pt, 0, a0); storeQ(pt, 1, a1); storeQ(pt, 2, a2); storeQ(pt, 3, a3);
        }
    }
    asm volatile("" ::: "memory");
    {
        const half8 A0 = wfrag[10*64+lane], A1 = wfrag[11*64+lane];
        const half8 A2 = wfrag[12*64+lane], A3 = wfrag[13*64+lane];
        const half8 A4 = wfrag[14*64+lane], A5 = wfrag[15*64+lane];
        const half8 A6 = wfrag[16*64+lane], A7 = wfrag[17*64+lane];
        #pragma unroll
        for (int nt = 0; nt < 2; ++nt) {
            const int pt = nt*16 + n;
            const half8 B0 = *(const half8*)&smM[w][pt][ 0 + 8*g];
            const half8 B1 = *(const half8*)&smM[w][pt][32 + 8*g];
            floatx4 a0 = MFMA16x16x32(A0, B0, zz, 0,0,0); a0 = MFMA16x16x32(A1, B1, a0, 0,0,0);
            floatx4 a1 = MFMA16x16x32(A2, B0, zz, 0,0,0); a1 = MFMA16x16x32(A3, B1, a1, 0,0,0);
            floatx4 a2 = MFMA16x16x32(A4, B0, zz, 0,0,0); a2 = MFMA16x16x32(A5, B1, a2, 0,0,0);
            floatx4 a3 = MFMA16x16x32(A6, B0, zz, 0,0,0); a3 = MFMA16x16x32(A7, B1, a3, 0,0,0);
            storeQ(pt, 0, a0); storeQ(pt, 1, a1); storeQ(pt, 2, a2); storeQ(pt, 3, a3);
        }
    }
    asm volatile("" ::: "memory");
    {
        const half8 A0 = wfrag[18*64+lane], A1 = wfrag[19*64+lane];
        #pragma unroll
        for (int nt = 0; nt < 2; ++nt) {
            const int pt = nt*16 + n;
            const half8 B0 = *(const half8*)&smM[w][pt][ 0 + 8*g];
            const half8 B1 = *(const half8*)&smM[w][pt][32 + 8*g];
            floatx4 acc = MFMA16x16x32(A0, B0, zz, 0,0,0);
            acc = MFMA16x16x32(A1, B1, acc, 0,0,0);
            if (g == 0) out[NPTS + gbase + pt] = fabsf(acc[0]);
        }
    }
}

extern "C" void kernel_launch(void* const* d_in, const int* in_sizes, int n_in,
                              void* d_out, int out_size, void* d_ws, size_t ws_size,
                              hipStream_t stream)
{
    const float* x   = (const float*)d_in[0];
    const float* d   = (const float*)d_in[1];
    const float* emb = (const float*)d_in[2];
    const float* ws0 = (const float*)d_in[3];
    const float* ws1 = (const float*)d_in[4];
    const float* wc0 = (const float*)d_in[5];
    const float* wc1 = (const float*)d_in[6];
    const float* wc2 = (const float*)d_in[7];
    float* out = (float*)d_out;

    half8* wfrag = (half8*)d_ws;                               // 20 KB
    _Float16* feats = (_Float16*)((char*)d_ws + 32768);        // 64 MB

    // Replicate numpy's host-side RESOLUTIONS computation bit-for-bit.
    int r[16];
    const double s = std::exp(std::log(4.0) / 15.0);
    for (int l = 0; l < 16; ++l)
        r[l] = (int)std::floor(16.0 * std::pow(s, (double)l));
    const int4 ra = {r[0],  r[1],  r[2],  r[3]};
    const int4 rb = {r[4],  r[5],  r[6],  r[7]};
    const int4 rc = {r[8],  r[9],  r[10], r[11]};
    const int4 rd = {r[12], r[13], r[14], r[15]};

    prepack_weights<<<20, 64, 0, stream>>>(ws0, ws1, wc0, wc1, wc2, wfrag);

    const size_t need = 32768 + (size_t)NPTS * 32 * sizeof(_Float16);
    if (ws_size >= need) {
        ngp_gather<<<NPTS * 4 / 256, 256, 0, stream>>>(x, emb, feats, ra, rb, rc, rd);
        ngp_mlp<<<NPTS / 128, 256, 0, stream>>>(d, feats, wfrag, out);
    } else {
        ngp_fused_fb<<<NPTS / 128, 256, 0, stream>>>(x, d, emb, wfrag, out, ra, rb, rc, rd);
    }
}

// Round 4
// 331.263 us; speedup vs baseline: 1.3092x; 1.3092x over previous
//
#include <hip/hip_runtime.h>
#include <cmath>

#define NPTS 1048576
#define TABLE_SZ 524288

typedef _Float16 half8 __attribute__((ext_vector_type(8)));
typedef _Float16 half4 __attribute__((ext_vector_type(4)));
typedef float floatx4 __attribute__((ext_vector_type(4)));
typedef float float4a8 __attribute__((ext_vector_type(4), aligned(8)));
typedef unsigned int uint2a4 __attribute__((ext_vector_type(2), aligned(4)));

#define MFMA16x16x32 __builtin_amdgcn_mfma_f32_16x16x32_f16

__device__ __forceinline__ float2 unpack_h2(unsigned int u) {
    union { unsigned int u; _Float16 h[2]; } c; c.u = u;
    return make_float2((float)c.h[0], (float)c.h[1]);
}

// ---------------------------------------------------------------------------
// Pre-pack all MLP weights into f16 MFMA A-fragments (W^T as A operand).
//   lane l holds row m = l&15, k = 32*kt + (l>>4)*8 + e, e in [0,8).
// ---------------------------------------------------------------------------
__global__ void prepack_weights(const float* __restrict__ ws0,
                                const float* __restrict__ ws1,
                                const float* __restrict__ wc0,
                                const float* __restrict__ wc1,
                                const float* __restrict__ wc2,
                                half8* __restrict__ wfrag)
{
    const int f = blockIdx.x, l = threadIdx.x;
    const float* W; int Kreal, Mreal, mt, kt;
    if (f < 4)       { W = ws0; Kreal = 32; Mreal = 64; mt = f;          kt = 0;        }
    else if (f < 6)  { W = ws1; Kreal = 64; Mreal = 16; mt = 0;          kt = f - 4;    }
    else if (f < 10) { W = wc0; Kreal = 31; Mreal = 64; mt = f - 6;      kt = 0;        }
    else if (f < 18) { W = wc1; Kreal = 64; Mreal = 64; mt = (f-10)>>1;  kt = (f-10)&1; }
    else             { W = wc2; Kreal = 64; Mreal = 1;  mt = 0;          kt = f - 18;   }

    const int m  = 16*mt + (l & 15);
    const int k0 = 32*kt + (l >> 4)*8;
    half8 hv;
    #pragma unroll
    for (int e = 0; e < 8; ++e) {
        const int k = k0 + e;
        const float v = (m < Mreal && k < Kreal) ? W[k*Mreal + m] : 0.0f;
        hv[e] = (_Float16)v;
    }
    wfrag[f*64 + l] = hv;
}

// ---------------------------------------------------------------------------
// Convert the ACTIVE region of each level's fp32 table to packed f16.
// Entry = 2 feats -> one uint (4B). Total ~1.25M entries (~5 MB).
// ---------------------------------------------------------------------------
__global__ __launch_bounds__(256) void convert_tables(
    const float* __restrict__ emb, unsigned int* __restrict__ tabu,
    int4 ra, int4 rb, int4 rc, int4 rd,
    int4 oa, int4 ob, int4 oc, int4 od)
{
    const int l = blockIdx.y;
    const int q = l >> 2, j = l & 3;
    const int4 rv = (q == 0) ? ra : (q == 1) ? rb : (q == 2) ? rc : rd;
    const int4 ov = (q == 0) ? oa : (q == 1) ? ob : (q == 2) ? oc : od;
    const int R   = (j == 0) ? rv.x : (j == 1) ? rv.y : (j == 2) ? rv.z : rv.w;
    const int off = (j == 0) ? ov.x : (j == 1) ? ov.y : (j == 2) ? ov.z : ov.w;
    const int n = (R+1)*(R+1)*(R+1);
    const int e = blockIdx.x * 256 + threadIdx.x;
    if (e >= n) return;
    const float2 v = *(const float2*)(emb + (size_t)l * (TABLE_SZ*2) + 2*(size_t)e);
    union { unsigned int u; _Float16 h[2]; } c;
    c.h[0] = (_Float16)v.x; c.h[1] = (_Float16)v.y;
    tabu[off + e] = c.u;
}

// ---------------------------------------------------------------------------
// Gather kernel: 4 threads/point, 4 levels/thread. Loads-first structure so
// all 16 x-pair loads (8B each, f16 tables) are in flight together.
// ---------------------------------------------------------------------------
__global__ __launch_bounds__(256, 4) void ngp_gather(
    const float* __restrict__ xin, const unsigned int* __restrict__ tabu,
    _Float16* __restrict__ feats,
    int4 ra, int4 rb, int4 rc, int4 rd,
    int4 oa, int4 ob, int4 oc, int4 od)
{
    const int tid = blockIdx.x * 256 + threadIdx.x;
    const int p = tid >> 2;            // point
    const int q = tid & 3;             // level quad: levels 4q..4q+3

    const float px = (xin[3*p+0] + 1.0f) * 0.5f;
    const float py = (xin[3*p+1] + 1.0f) * 0.5f;
    const float pz = (xin[3*p+2] + 1.0f) * 0.5f;

    const int4 rv = (q == 0) ? ra : (q == 1) ? rb : (q == 2) ? rc : rd;
    const int4 ov = (q == 0) ? oa : (q == 1) ? ob : (q == 2) ? oc : od;

    uint2a4 P[16];
    float fx[4], fy[4], fz[4];

    #pragma unroll
    for (int j = 0; j < 4; ++j) {
        const int R   = (j == 0) ? rv.x : (j == 1) ? rv.y : (j == 2) ? rv.z : rv.w;
        const int off = (j == 0) ? ov.x : (j == 1) ? ov.y : (j == 2) ? ov.z : ov.w;
        const float Rf = (float)R;
        const float gx = px*Rf, gy = py*Rf, gz = pz*Rf;
        int x0 = (int)floorf(gx); x0 = x0 < 0 ? 0 : (x0 > R-1 ? R-1 : x0);
        int y0 = (int)floorf(gy); y0 = y0 < 0 ? 0 : (y0 > R-1 ? R-1 : y0);
        int z0 = (int)floorf(gz); z0 = z0 < 0 ? 0 : (z0 > R-1 ? R-1 : z0);
        fx[j] = gx - (float)x0; fy[j] = gy - (float)y0; fz[j] = gz - (float)z0;
        const int s1 = R + 1, s2 = s1 * s1;
        const unsigned int* tab = tabu + off;
        const int b = x0 + y0*s1 + z0*s2;
        P[4*j+0] = *(const uint2a4*)(tab + b);
        P[4*j+1] = *(const uint2a4*)(tab + b + s1);
        P[4*j+2] = *(const uint2a4*)(tab + b + s2);
        P[4*j+3] = *(const uint2a4*)(tab + b + s1 + s2);
    }

    half8 hv;
    #pragma unroll
    for (int j = 0; j < 4; ++j) {
        const float2 c000 = unpack_h2(P[4*j+0].x), c100 = unpack_h2(P[4*j+0].y);
        const float2 c010 = unpack_h2(P[4*j+1].x), c110 = unpack_h2(P[4*j+1].y);
        const float2 c001 = unpack_h2(P[4*j+2].x), c101 = unpack_h2(P[4*j+2].y);
        const float2 c011 = unpack_h2(P[4*j+3].x), c111 = unpack_h2(P[4*j+3].y);
        const float fxj = fx[j], fyj = fy[j], fzj = fz[j];
        const float a00x = fmaf(fxj, c100.x - c000.x, c000.x);
        const float a00y = fmaf(fxj, c100.y - c000.y, c000.y);
        const float a10x = fmaf(fxj, c110.x - c010.x, c010.x);
        const float a10y = fmaf(fxj, c110.y - c010.y, c010.y);
        const float a01x = fmaf(fxj, c101.x - c001.x, c001.x);
        const float a01y = fmaf(fxj, c101.y - c001.y, c001.y);
        const float a11x = fmaf(fxj, c111.x - c011.x, c011.x);
        const float a11y = fmaf(fxj, c111.y - c011.y, c011.y);
        const float b0x = fmaf(fyj, a10x - a00x, a00x);
        const float b1x = fmaf(fyj, a11x - a01x, a01x);
        const float b0y = fmaf(fyj, a10y - a00y, a00y);
        const float b1y = fmaf(fyj, a11y - a01y, a01y);
        hv[2*j+0] = (_Float16)fmaf(fzj, b1x - b0x, b0x);
        hv[2*j+1] = (_Float16)fmaf(fzj, b1y - b0y, b0y);
    }
    *(half8*)&feats[(size_t)p*32 + q*8] = hv;
}

// ---------------------------------------------------------------------------
// MLP kernel. 4 waves/block, 32 points/wave (wave-private LDS, no
// __syncthreads). Layers computed as Y^T = W^T @ X^T.
// ---------------------------------------------------------------------------
__global__ __launch_bounds__(256) void ngp_mlp(
    const float* __restrict__ din, const _Float16* __restrict__ feats,
    const half8* __restrict__ wfrag, float* __restrict__ out)
{
    __shared__ __align__(16) _Float16 smM[4][32][72];  // H / c1 / c2
    __shared__ __align__(16) _Float16 smG[4][32][24];  // geo feats (hd 16-31)

    const int tid  = threadIdx.x;
    const int w    = tid >> 6, lane = tid & 63;
    const int gbase = (blockIdx.x * 4 + w) * 32;

    const int n = lane & 15, g = lane >> 4;
    const floatx4 zz = {0.f, 0.f, 0.f, 0.f};

    auto storeQ = [&](int pt, int mt, floatx4 a) {
        half4 hv;
        hv[0] = (_Float16)fmaxf(a[0], 0.f); hv[1] = (_Float16)fmaxf(a[1], 0.f);
        hv[2] = (_Float16)fmaxf(a[2], 0.f); hv[3] = (_Float16)fmaxf(a[3], 0.f);
        *(half4*)&smM[w][pt][16*mt + 4*g] = hv;
    };

    // S0: feats[32] @ ws0 -> H[64], relu
    {
        const half8 A0 = wfrag[0*64+lane], A1 = wfrag[1*64+lane];
        const half8 A2 = wfrag[2*64+lane], A3 = wfrag[3*64+lane];
        #pragma unroll
        for (int nt = 0; nt < 2; ++nt) {
            const int pt = nt*16 + n;
            const half8 B = *(const half8*)&feats[(size_t)(gbase + pt)*32 + 8*g];
            floatx4 a0 = MFMA16x16x32(A0, B, zz, 0,0,0);
            floatx4 a1 = MFMA16x16x32(A1, B, zz, 0,0,0);
            floatx4 a2 = MFMA16x16x32(A2, B, zz, 0,0,0);
            floatx4 a3 = MFMA16x16x32(A3, B, zz, 0,0,0);
            storeQ(pt, 0, a0); storeQ(pt, 1, a1); storeQ(pt, 2, a2); storeQ(pt, 3, a3);
        }
    }
    asm volatile("" ::: "memory");

    // S1: H[64] @ ws1 -> G[16] (linear); sigma + geo out
    {
        const half8 A0 = wfrag[4*64+lane], A1 = wfrag[5*64+lane];
        #pragma unroll
        for (int nt = 0; nt < 2; ++nt) {
            const int pt = nt*16 + n;
            const half8 B0 = *(const half8*)&smM[w][pt][ 0 + 8*g];
            const half8 B1 = *(const half8*)&smM[w][pt][32 + 8*g];
            floatx4 acc = MFMA16x16x32(A0, B0, zz, 0,0,0);
            acc = MFMA16x16x32(A1, B1, acc, 0,0,0);
            if (g == 0) {
                out[gbase + pt] = fabsf(acc[0]);             // sigma = |g0|
                smG[w][pt][0]  = (_Float16)acc[1];
                smG[w][pt][1]  = (_Float16)acc[2];
                smG[w][pt][2]  = (_Float16)acc[3];
                smG[w][pt][15] = (_Float16)0.f;              // hd[31] pad
            } else {
                smG[w][pt][4*g-1] = (_Float16)acc[0];
                smG[w][pt][4*g+0] = (_Float16)acc[1];
                smG[w][pt][4*g+1] = (_Float16)acc[2];
                smG[w][pt][4*g+2] = (_Float16)acc[3];
            }
        }
    }
    asm volatile("" ::: "memory");

    // C0: hd[32] @ wc0 -> c1[64], relu
    {
        const half8 A0 = wfrag[6*64+lane], A1 = wfrag[7*64+lane];
        const half8 A2 = wfrag[8*64+lane], A3 = wfrag[9*64+lane];
        #pragma unroll
        for (int nt = 0; nt < 2; ++nt) {
            const int pt = nt*16 + n;
            half8 B;
            if (g < 2) {
                const int gpt = gbase + pt;
                const float x = din[3*gpt+0], y = din[3*gpt+1], z = din[3*gpt+2];
                const float xx = x*x, yy = y*y, zzq = z*z;
                const float xy = x*y, yz = y*z, xz = x*z;
                float s[8];
                if (g == 0) {
                    s[0] = 0.28209479177387814f;
                    s[1] = -0.48860251190291987f * y;
                    s[2] =  0.48860251190291987f * z;
                    s[3] = -0.48860251190291987f * x;
                    s[4] =  1.0925484305920792f * xy;
                    s[5] = -1.0925484305920792f * yz;
                    s[6] =  0.94617469575756f * zzq - 0.31539156525252005f;
                    s[7] = -1.0925484305920792f * xz;
                } else {
                    s[0] =  0.5462742152960396f * (xx - yy);
                    s[1] =  0.5900435899266435f * y * (yy - 3.0f*xx);
                    s[2] =  2.890611442640554f * xy * z;
                    s[3] =  0.4570457994644657f * y * (1.0f - 5.0f*zzq);
                    s[4] =  0.3731763325901154f * z * (5.0f*zzq - 3.0f);
                    s[5] =  0.4570457994644657f * x * (1.0f - 5.0f*zzq);
                    s[6] =  1.445305721320277f * z * (xx - yy);
                    s[7] =  0.5900435899266435f * x * (3.0f*yy - xx);
                }
                #pragma unroll
                for (int e = 0; e < 8; ++e) B[e] = (_Float16)s[e];
            } else {
                B = *(const half8*)&smG[w][pt][8*(g-2)];
            }
            floatx4 a0 = MFMA16x16x32(A0, B, zz, 0,0,0);
            floatx4 a1 = MFMA16x16x32(A1, B, zz, 0,0,0);
            floatx4 a2 = MFMA16x16x32(A2, B, zz, 0,0,0);
            floatx4 a3 = MFMA16x16x32(A3, B, zz, 0,0,0);
            storeQ(pt, 0, a0); storeQ(pt, 1, a1); storeQ(pt, 2, a2); storeQ(pt, 3, a3);
        }
    }
    asm volatile("" ::: "memory");

    // C1: c1[64] @ wc1 -> c2[64], relu
    {
        const half8 A0 = wfrag[10*64+lane], A1 = wfrag[11*64+lane];
        const half8 A2 = wfrag[12*64+lane], A3 = wfrag[13*64+lane];
        const half8 A4 = wfrag[14*64+lane], A5 = wfrag[15*64+lane];
        const half8 A6 = wfrag[16*64+lane], A7 = wfrag[17*64+lane];
        #pragma unroll
        for (int nt = 0; nt < 2; ++nt) {
            const int pt = nt*16 + n;
            const half8 B0 = *(const half8*)&smM[w][pt][ 0 + 8*g];
            const half8 B1 = *(const half8*)&smM[w][pt][32 + 8*g];
            floatx4 a0 = MFMA16x16x32(A0, B0, zz, 0,0,0); a0 = MFMA16x16x32(A1, B1, a0, 0,0,0);
            floatx4 a1 = MFMA16x16x32(A2, B0, zz, 0,0,0); a1 = MFMA16x16x32(A3, B1, a1, 0,0,0);
            floatx4 a2 = MFMA16x16x32(A4, B0, zz, 0,0,0); a2 = MFMA16x16x32(A5, B1, a2, 0,0,0);
            floatx4 a3 = MFMA16x16x32(A6, B0, zz, 0,0,0); a3 = MFMA16x16x32(A7, B1, a3, 0,0,0);
            storeQ(pt, 0, a0); storeQ(pt, 1, a1); storeQ(pt, 2, a2); storeQ(pt, 3, a3);
        }
    }
    asm volatile("" ::: "memory");

    // C2: c2[64] @ wc2 -> color (|.|)
    {
        const half8 A0 = wfrag[18*64+lane], A1 = wfrag[19*64+lane];
        #pragma unroll
        for (int nt = 0; nt < 2; ++nt) {
            const int pt = nt*16 + n;
            const half8 B0 = *(const half8*)&smM[w][pt][ 0 + 8*g];
            const half8 B1 = *(const half8*)&smM[w][pt][32 + 8*g];
            floatx4 acc = MFMA16x16x32(A0, B0, zz, 0,0,0);
            acc = MFMA16x16x32(A1, B1, acc, 0,0,0);
            if (g == 0) out[NPTS + gbase + pt] = fabsf(acc[0]);
        }
    }
}

// ---------------------------------------------------------------------------
// Fallback fused kernel for small ws_size (round-2 structure, fp32 tables).
// ---------------------------------------------------------------------------
__global__ __launch_bounds__(256) void ngp_fused_fb(
    const float* __restrict__ xin, const float* __restrict__ din,
    const float* __restrict__ emb, const half8* __restrict__ wfrag,
    float* __restrict__ out, int4 ra, int4 rb, int4 rc, int4 rd)
{
    __shared__ __align__(16) _Float16 smM[4][32][72];
    __shared__ __align__(16) _Float16 smG[4][32][24];
    const int tid  = threadIdx.x;
    const int w    = tid >> 6, lane = tid & 63;
    const int gbase = (blockIdx.x * 4 + w) * 32;
    {
        const int p  = lane & 31, hi = lane >> 5;
        const int gpt = gbase + p;
        const float px = (xin[3*gpt+0] + 1.0f) * 0.5f;
        const float py = (xin[3*gpt+1] + 1.0f) * 0.5f;
        const float pz = (xin[3*gpt+2] + 1.0f) * 0.5f;
        float ft[16];
        #pragma unroll
        for (int j = 0; j < 8; ++j) {
            int R;
            if      (j == 0) R = hi ? rc.x : ra.x;
            else if (j == 1) R = hi ? rc.y : ra.y;
            else if (j == 2) R = hi ? rc.z : ra.z;
            else if (j == 3) R = hi ? rc.w : ra.w;
            else if (j == 4) R = hi ? rd.x : rb.x;
            else if (j == 5) R = hi ? rd.y : rb.y;
            else if (j == 6) R = hi ? rd.z : rb.z;
            else             R = hi ? rd.w : rb.w;
            const int lv = hi*8 + j;
            const float Rf = (float)R;
            const float gx = px*Rf, gy = py*Rf, gz = pz*Rf;
            int x0 = (int)floorf(gx); x0 = x0 < 0 ? 0 : (x0 > R-1 ? R-1 : x0);
            int y0 = (int)floorf(gy); y0 = y0 < 0 ? 0 : (y0 > R-1 ? R-1 : y0);
            int z0 = (int)floorf(gz); z0 = z0 < 0 ? 0 : (z0 > R-1 ? R-1 : z0);
            const float fx = gx - (float)x0, fy = gy - (float)y0, fz = gz - (float)z0;
            const int s1 = R + 1, s2 = s1 * s1;
            const float* tab = emb + (size_t)lv * (size_t)(TABLE_SZ * 2);
            const int b = x0 + y0*s1 + z0*s2;
            const float4a8 P00 = *(const float4a8*)(tab + 2*(b));
            const float4a8 P10 = *(const float4a8*)(tab + 2*(b + s1));
            const float4a8 P01 = *(const float4a8*)(tab + 2*(b + s2));
            const float4a8 P11 = *(const float4a8*)(tab + 2*(b + s1 + s2));
            const float a00x = fmaf(fx, P00.z - P00.x, P00.x);
            const float a00y = fmaf(fx, P00.w - P00.y, P00.y);
            const float a10x = fmaf(fx, P10.z - P10.x, P10.x);
            const float a10y = fmaf(fx, P10.w - P10.y, P10.y);
            const float a01x = fmaf(fx, P01.z - P01.x, P01.x);
            const float a01y = fmaf(fx, P01.w - P01.y, P01.y);
            const float a11x = fmaf(fx, P11.z - P11.x, P11.x);
            const float a11y = fmaf(fx, P11.w - P11.y, P11.y);
            const float b0x = fmaf(fy, a10x - a00x, a00x);
            const float b1x = fmaf(fy, a11x - a01x, a01x);
            const float b0y = fmaf(fy, a10y - a00y, a00y);
            const float b1y = fmaf(fy, a11y - a01y, a01y);
            ft[2*j+0] = fmaf(fz, b1x - b0x, b0x);
            ft[2*j+1] = fmaf(fz, b1y - b0y, b0y);
        }
        half8 v0, v1;
        #pragma unroll
        for (int c = 0; c < 8; ++c) { v0[c] = (_Float16)ft[c]; v1[c] = (_Float16)ft[8+c]; }
        *(half8*)&smM[w][p][16*hi + 0] = v0;
        *(half8*)&smM[w][p][16*hi + 8] = v1;
    }
    asm volatile("" ::: "memory");
    const int n = lane & 15, g = lane >> 4;
    const floatx4 zz = {0.f, 0.f, 0.f, 0.f};
    auto storeQ = [&](int pt, int mt, floatx4 a) {
        half4 hv;
        hv[0] = (_Float16)fmaxf(a[0], 0.f); hv[1] = (_Float16)fmaxf(a[1], 0.f);
        hv[2] = (_Float16)fmaxf(a[2], 0.f); hv[3] = (_Float16)fmaxf(a[3], 0.f);
        *(half4*)&smM[w][pt][16*mt + 4*g] = hv;
    };
    {
        const half8 A0 = wfrag[0*64+lane], A1 = wfrag[1*64+lane];
        const half8 A2 = wfrag[2*64+lane], A3 = wfrag[3*64+lane];
        #pragma unroll
        for (int nt = 0; nt < 2; ++nt) {
            const int pt = nt*16 + n;
            const half8 B = *(const half8*)&smM[w][pt][8*g];
            floatx4 a0 = MFMA16x16x32(A0, B, zz, 0,0,0);
            floatx4 a1 = MFMA16x16x32(A1, B, zz, 0,0,0);
            floatx4 a2 = MFMA16x16x32(A2, B, zz, 0,0,0);
            floatx4 a3 = MFMA16x16x32(A3, B, zz, 0,0,0);
            storeQ(pt, 0, a0); storeQ(pt, 1, a1); storeQ(pt, 2, a2); storeQ(pt, 3, a3);
        }
    }
    asm volatile("" ::: "memory");
    {
        const half8 A0 = wfrag[4*64+lane], A1 = wfrag[5*64+lane];
        #pragma unroll
        for (int nt = 0; nt < 2; ++nt) {
            const int pt = nt*16 + n;
            const half8 B0 = *(const half8*)&smM[w][pt][ 0 + 8*g];
            const half8 B1 = *(const half8*)&smM[w][pt][32 + 8*g];
            floatx4 acc = MFMA16x16x32(A0, B0, zz, 0,0,0);
            acc = MFMA16x16x32(A1, B1, acc, 0,0,0);
            if (g == 0) {
                out[gbase + pt] = fabsf(acc[0]);
                smG[w][pt][0]  = (_Float16)acc[1];
                smG[w][pt][1]  = (_Float16)acc[2];
                smG[w][pt][2]  = (_Float16)acc[3];
                smG[w][pt][15] = (_Float16)0.f;
            } else {
                smG[w][pt][4*g-1] = (_Float16)acc[0];
                smG[w][pt][4*g+0] = (_Float16)acc[1];
                smG[w][pt][4*g+1] = (_Float16)acc[2];
                smG[w][pt][4*g+2] = (_Float16)acc[3];
            }
        }
    }
    asm volatile("" ::: "memory");
    {
        const half8 A0 = wfrag[6*64+lane], A1 = wfrag[7*64+lane];
        const half8 A2 = wfrag[8*64+lane], A3 = wfrag[9*64+lane];
        #pragma unroll
        for (int nt = 0; nt < 2; ++nt) {
            const int pt = nt*16 + n;
            half8 B;
            if (g < 2) {
                const int gpt = gbase + pt;
                const float x = din[3*gpt+0], y = din[3*gpt+1], z = din[3*gpt+2];
                const float xx = x*x, yy = y*y, zzq = z*z;
                const float xy = x*y, yz = y*z, xz = x*z;
                float s[8];
                if (g == 0) {
                    s[0] = 0.28209479177387814f;
                    s[1] = -0.48860251190291987f * y;
                    s[2] =  0.48860251190291987f * z;
                    s[3] = -0.48860251190291987f * x;
                    s[4] =  1.0925484305920792f * xy;
                    s[5] = -1.0925484305920792f * yz;
                    s[6] =  0.94617469575756f * zzq - 0.31539156525252005f;
                    s[7] = -1.0925484305920792f * xz;
                } else {
                    s[0] =  0.5462742152960396f * (xx - yy);
                    s[1] =  0.5900435899266435f * y * (yy - 3.0f*xx);
                    s[2] =  2.890611442640554f * xy * z;
                    s[3] =  0.4570457994644657f * y * (1.0f - 5.0f*zzq);
                    s[4] =  0.3731763325901154f * z * (5.0f*zzq - 3.0f);
                    s[5] =  0.4570457994644657f * x * (1.0f - 5.0f*zzq);
                    s[6] =  1.445305721320277f * z * (xx - yy);
                    s[7] =  0.5900435899266435f * x * (3.0f*yy - xx);
                }
                #pragma unroll
                for (int e = 0; e < 8; ++e) B[e] = (_Float16)s[e];
            } else {
                B = *(const half8*)&smG[w][pt][8*(g-2)];
            }
            floatx4 a0 = MFMA16x16x32(A0, B, zz, 0,0,0);
            floatx4 a1 = MFMA16x16x32(A1, B, zz, 0,0,0);
            floatx4 a2 = MFMA16x16x32(A2, B, zz, 0,0,0);
            floatx4 a3 = MFMA16x16x32(A3, B, zz, 0,0,0);
            storeQ(pt, 0, a0); storeQ(pt, 1, a1); storeQ(pt, 2, a2); storeQ(pt, 3, a3);
        }
    }
    asm volatile("" ::: "memory");
    {
        const half8 A0 = wfrag[10*64+lane], A1 = wfrag[11*64+lane];
        const half8 A2 = wfrag[12*64+lane], A3 = wfrag[13*64+lane];
        const half8 A4 = wfrag[14*64+lane], A5 = wfrag[15*64+lane];
        const half8 A6 = wfrag[16*64+lane], A7 = wfrag[17*64+lane];
        #pragma unroll
        for (int nt = 0; nt < 2; ++nt) {
            const int pt = nt*16 + n;
            const half8 B0 = *(const half8*)&smM[w][pt][ 0 + 8*g];
            const half8 B1 = *(const half8*)&smM[w][pt][32 + 8*g];
            floatx4 a0 = MFMA16x16x32(A0, B0, zz, 0,0,0); a0 = MFMA16x16x32(A1, B1, a0, 0,0,0);
            floatx4 a1 = MFMA16x16x32(A2, B0, zz, 0,0,0); a1 = MFMA16x16x32(A3, B1, a1, 0,0,0);
            floatx4 a2 = MFMA16x16x32(A4, B0, zz, 0,0,0); a2 = MFMA16x16x32(A5, B1, a2, 0,0,0);
            floatx4 a3 = MFMA16x16x32(A6, B0, zz, 0,0,0); a3 = MFMA16x16x32(A7, B1, a3, 0,0,0);
            storeQ(pt, 0, a0); storeQ(pt, 1, a1); storeQ(pt, 2, a2); storeQ(pt, 3, a3);
        }
    }
    asm volatile("" ::: "memory");
    {
        const half8 A0 = wfrag[18*64+lane], A1 = wfrag[19*64+lane];
        #pragma unroll
        for (int nt = 0; nt < 2; ++nt) {
            const int pt = nt*16 + n;
            const half8 B0 = *(const half8*)&smM[w][pt][ 0 + 8*g];
            const half8 B1 = *(const half8*)&smM[w][pt][32 + 8*g];
            floatx4 acc = MFMA16x16x32(A0, B0, zz, 0,0,0);
            acc = MFMA16x16x32(A1, B1, acc, 0,0,0);
            if (g == 0) out[NPTS + gbase + pt] = fabsf(acc[0]);
        }
    }
}

extern "C" void kernel_launch(void* const* d_in, const int* in_sizes, int n_in,
                              void* d_out, int out_size, void* d_ws, size_t ws_size,
                              hipStream_t stream)
{
    const float* x   = (const float*)d_in[0];
    const float* d   = (const float*)d_in[1];
    const float* emb = (const float*)d_in[2];
    const float* ws0 = (const float*)d_in[3];
    const float* ws1 = (const float*)d_in[4];
    const float* wc0 = (const float*)d_in[5];
    const float* wc1 = (const float*)d_in[6];
    const float* wc2 = (const float*)d_in[7];
    float* out = (float*)d_out;

    // workspace layout: [0,32K) wfrag | [32K, 32K+8M) f16 tables | feats 64MB
    half8* wfrag = (half8*)d_ws;
    unsigned int* tabu = (unsigned int*)((char*)d_ws + 32768);
    _Float16* feats = (_Float16*)((char*)d_ws + 32768 + 8388608);

    // Replicate numpy's host-side RESOLUTIONS computation bit-for-bit.
    int r[16], off[16];
    const double s = std::exp(std::log(4.0) / 15.0);
    int acc = 0;
    for (int l = 0; l < 16; ++l) {
        r[l] = (int)std::floor(16.0 * std::pow(s, (double)l));
        off[l] = acc;
        acc += (r[l]+1)*(r[l]+1)*(r[l]+1);
    }
    const int4 ra = {r[0],  r[1],  r[2],  r[3]};
    const int4 rb = {r[4],  r[5],  r[6],  r[7]};
    const int4 rc = {r[8],  r[9],  r[10], r[11]};
    const int4 rd = {r[12], r[13], r[14], r[15]};
    const int4 oa = {off[0],  off[1],  off[2],  off[3]};
    const int4 ob = {off[4],  off[5],  off[6],  off[7]};
    const int4 oc = {off[8],  off[9],  off[10], off[11]};
    const int4 od = {off[12], off[13], off[14], off[15]};

    prepack_weights<<<20, 64, 0, stream>>>(ws0, ws1, wc0, wc1, wc2, wfrag);

    const size_t need = 32768 + 8388608 + (size_t)NPTS * 32 * sizeof(_Float16);
    if (ws_size >= need) {
        const int nmax = (r[15]+1)*(r[15]+1)*(r[15]+1);
        dim3 cgrid((nmax + 255) / 256, 16);
        convert_tables<<<cgrid, 256, 0, stream>>>(emb, tabu, ra, rb, rc, rd, oa, ob, oc, od);
        ngp_gather<<<NPTS * 4 / 256, 256, 0, stream>>>(x, tabu, feats, ra, rb, rc, rd, oa, ob, oc, od);
        ngp_mlp<<<NPTS / 128, 256, 0, stream>>>(d, feats, wfrag, out);
    } else {
        ngp_fused_fb<<<NPTS / 128, 256, 0, stream>>>(x, d, emb, wfrag, out, ra, rb, rc, rd);
    }
}

// Round 5
// 264.131 us; speedup vs baseline: 1.6420x; 1.2542x over previous
//
#include <hip/hip_runtime.h>
#include <cmath>

#define NPTS 1048576
#define TABLE_SZ 524288
#define NBUCK 32768   // 32^3 spatial buckets

typedef _Float16 half8 __attribute__((ext_vector_type(8)));
typedef _Float16 half4 __attribute__((ext_vector_type(4)));
typedef float floatx4 __attribute__((ext_vector_type(4)));
typedef float float4a8 __attribute__((ext_vector_type(4), aligned(8)));
typedef unsigned int uint2a4 __attribute__((ext_vector_type(2), aligned(4)));

#define MFMA16x16x32 __builtin_amdgcn_mfma_f32_16x16x32_f16

__device__ __forceinline__ float2 unpack_h2(unsigned int u) {
    union { unsigned int u; _Float16 h[2]; } c; c.u = u;
    return make_float2((float)c.h[0], (float)c.h[1]);
}

// ---------------------------------------------------------------------------
// Pre-pack all MLP weights into f16 MFMA A-fragments (W^T as A operand).
//   lane l holds row m = l&15, k = 32*kt + (l>>4)*8 + e, e in [0,8).
// ---------------------------------------------------------------------------
__global__ void prepack_weights(const float* __restrict__ ws0,
                                const float* __restrict__ ws1,
                                const float* __restrict__ wc0,
                                const float* __restrict__ wc1,
                                const float* __restrict__ wc2,
                                half8* __restrict__ wfrag)
{
    const int f = blockIdx.x, l = threadIdx.x;
    const float* W; int Kreal, Mreal, mt, kt;
    if (f < 4)       { W = ws0; Kreal = 32; Mreal = 64; mt = f;          kt = 0;        }
    else if (f < 6)  { W = ws1; Kreal = 64; Mreal = 16; mt = 0;          kt = f - 4;    }
    else if (f < 10) { W = wc0; Kreal = 31; Mreal = 64; mt = f - 6;      kt = 0;        }
    else if (f < 18) { W = wc1; Kreal = 64; Mreal = 64; mt = (f-10)>>1;  kt = (f-10)&1; }
    else             { W = wc2; Kreal = 64; Mreal = 1;  mt = 0;          kt = f - 18;   }

    const int m  = 16*mt + (l & 15);
    const int k0 = 32*kt + (l >> 4)*8;
    half8 hv;
    #pragma unroll
    for (int e = 0; e < 8; ++e) {
        const int k = k0 + e;
        const float v = (m < Mreal && k < Kreal) ? W[k*Mreal + m] : 0.0f;
        hv[e] = (_Float16)v;
    }
    wfrag[f*64 + l] = hv;
}

// ---------------------------------------------------------------------------
// Convert the ACTIVE region of each level's fp32 table to packed f16.
// ---------------------------------------------------------------------------
__global__ __launch_bounds__(256) void convert_tables(
    const float* __restrict__ emb, unsigned int* __restrict__ tabu,
    int4 ra, int4 rb, int4 rc, int4 rd,
    int4 oa, int4 ob, int4 oc, int4 od)
{
    const int l = blockIdx.y;
    const int q = l >> 2, j = l & 3;
    const int4 rv = (q == 0) ? ra : (q == 1) ? rb : (q == 2) ? rc : rd;
    const int4 ov = (q == 0) ? oa : (q == 1) ? ob : (q == 2) ? oc : od;
    const int R   = (j == 0) ? rv.x : (j == 1) ? rv.y : (j == 2) ? rv.z : rv.w;
    const int off = (j == 0) ? ov.x : (j == 1) ? ov.y : (j == 2) ? ov.z : ov.w;
    const int n = (R+1)*(R+1)*(R+1);
    const int e = blockIdx.x * 256 + threadIdx.x;
    if (e >= n) return;
    const float2 v = *(const float2*)(emb + (size_t)l * (TABLE_SZ*2) + 2*(size_t)e);
    union { unsigned int u; _Float16 h[2]; } c;
    c.h[0] = (_Float16)v.x; c.h[1] = (_Float16)v.y;
    tabu[off + e] = c.u;
}

// ---------------------------------------------------------------------------
// Spatial counting sort (32^3 buckets)
// ---------------------------------------------------------------------------
__device__ __forceinline__ int bucket_of(float px, float py, float pz) {
    int bx = (int)(px * 32.0f); bx = bx < 0 ? 0 : (bx > 31 ? 31 : bx);
    int by = (int)(py * 32.0f); by = by < 0 ? 0 : (by > 31 ? 31 : by);
    int bz = (int)(pz * 32.0f); bz = bz < 0 ? 0 : (bz > 31 ? 31 : bz);
    return bx | (by << 5) | (bz << 10);
}

__global__ __launch_bounds__(256) void hist_kernel(
    const float* __restrict__ xin, unsigned int* __restrict__ hist)
{
    const int i = blockIdx.x * 256 + threadIdx.x;
    const float px = (xin[3*i+0] + 1.0f) * 0.5f;
    const float py = (xin[3*i+1] + 1.0f) * 0.5f;
    const float pz = (xin[3*i+2] + 1.0f) * 0.5f;
    atomicAdd(&hist[bucket_of(px, py, pz)], 1u);
}

__global__ __launch_bounds__(1024) void scan_kernel(
    const unsigned int* __restrict__ hist, unsigned int* __restrict__ off)
{
    __shared__ unsigned int ssum[1024];
    const int t = threadIdx.x;
    unsigned int v[32];
    unsigned int s = 0;
    #pragma unroll
    for (int j = 0; j < 32; ++j) {
        const unsigned int h = hist[t*32 + j];
        v[j] = s; s += h;
    }
    ssum[t] = s;
    __syncthreads();
    for (int d = 1; d < 1024; d <<= 1) {
        const unsigned int add = (t >= d) ? ssum[t-d] : 0u;
        __syncthreads();
        ssum[t] += add;
        __syncthreads();
    }
    const unsigned int base = (t == 0) ? 0u : ssum[t-1];
    #pragma unroll
    for (int j = 0; j < 32; ++j) off[t*32 + j] = base + v[j];
}

__global__ __launch_bounds__(256) void scatter_kernel(
    const float* __restrict__ xin, unsigned int* __restrict__ off,
    float4* __restrict__ xs4)
{
    const int i = blockIdx.x * 256 + threadIdx.x;
    const float px = (xin[3*i+0] + 1.0f) * 0.5f;
    const float py = (xin[3*i+1] + 1.0f) * 0.5f;
    const float pz = (xin[3*i+2] + 1.0f) * 0.5f;
    const int b = bucket_of(px, py, pz);
    const unsigned int pos = atomicAdd(&off[b], 1u);
    xs4[pos] = make_float4(px, py, pz, __uint_as_float((unsigned int)i));
}

// ---------------------------------------------------------------------------
// Gather over SORTED points: 4 threads/point, 4 levels/thread, loads-first.
// Feats written back to ORIGINAL point index (64B contiguous per point).
// ---------------------------------------------------------------------------
__global__ __launch_bounds__(256, 4) void ngp_gather_sorted(
    const float4* __restrict__ xs4, const unsigned int* __restrict__ tabu,
    _Float16* __restrict__ feats,
    int4 ra, int4 rb, int4 rc, int4 rd,
    int4 oa, int4 ob, int4 oc, int4 od)
{
    const int tid = blockIdx.x * 256 + threadIdx.x;
    const int p = tid >> 2;            // sorted position
    const int q = tid & 3;             // level quad: levels 4q..4q+3

    const float4 xv = xs4[p];
    const float px = xv.x, py = xv.y, pz = xv.z;
    const unsigned int orig = __float_as_uint(xv.w);

    const int4 rv = (q == 0) ? ra : (q == 1) ? rb : (q == 2) ? rc : rd;
    const int4 ov = (q == 0) ? oa : (q == 1) ? ob : (q == 2) ? oc : od;

    uint2a4 P[16];
    float fx[4], fy[4], fz[4];

    #pragma unroll
    for (int j = 0; j < 4; ++j) {
        const int R   = (j == 0) ? rv.x : (j == 1) ? rv.y : (j == 2) ? rv.z : rv.w;
        const int off = (j == 0) ? ov.x : (j == 1) ? ov.y : (j == 2) ? ov.z : ov.w;
        const float Rf = (float)R;
        const float gx = px*Rf, gy = py*Rf, gz = pz*Rf;
        int x0 = (int)floorf(gx); x0 = x0 < 0 ? 0 : (x0 > R-1 ? R-1 : x0);
        int y0 = (int)floorf(gy); y0 = y0 < 0 ? 0 : (y0 > R-1 ? R-1 : y0);
        int z0 = (int)floorf(gz); z0 = z0 < 0 ? 0 : (z0 > R-1 ? R-1 : z0);
        fx[j] = gx - (float)x0; fy[j] = gy - (float)y0; fz[j] = gz - (float)z0;
        const int s1 = R + 1, s2 = s1 * s1;
        const unsigned int* tab = tabu + off;
        const int b = x0 + y0*s1 + z0*s2;
        P[4*j+0] = *(const uint2a4*)(tab + b);
        P[4*j+1] = *(const uint2a4*)(tab + b + s1);
        P[4*j+2] = *(const uint2a4*)(tab + b + s2);
        P[4*j+3] = *(const uint2a4*)(tab + b + s1 + s2);
    }

    half8 hv;
    #pragma unroll
    for (int j = 0; j < 4; ++j) {
        const float2 c000 = unpack_h2(P[4*j+0].x), c100 = unpack_h2(P[4*j+0].y);
        const float2 c010 = unpack_h2(P[4*j+1].x), c110 = unpack_h2(P[4*j+1].y);
        const float2 c001 = unpack_h2(P[4*j+2].x), c101 = unpack_h2(P[4*j+2].y);
        const float2 c011 = unpack_h2(P[4*j+3].x), c111 = unpack_h2(P[4*j+3].y);
        const float fxj = fx[j], fyj = fy[j], fzj = fz[j];
        const float a00x = fmaf(fxj, c100.x - c000.x, c000.x);
        const float a00y = fmaf(fxj, c100.y - c000.y, c000.y);
        const float a10x = fmaf(fxj, c110.x - c010.x, c010.x);
        const float a10y = fmaf(fxj, c110.y - c010.y, c010.y);
        const float a01x = fmaf(fxj, c101.x - c001.x, c001.x);
        const float a01y = fmaf(fxj, c101.y - c001.y, c001.y);
        const float a11x = fmaf(fxj, c111.x - c011.x, c011.x);
        const float a11y = fmaf(fxj, c111.y - c011.y, c011.y);
        const float b0x = fmaf(fyj, a10x - a00x, a00x);
        const float b1x = fmaf(fyj, a11x - a01x, a01x);
        const float b0y = fmaf(fyj, a10y - a00y, a00y);
        const float b1y = fmaf(fyj, a11y - a01y, a01y);
        hv[2*j+0] = (_Float16)fmaf(fzj, b1x - b0x, b0x);
        hv[2*j+1] = (_Float16)fmaf(fzj, b1y - b0y, b0y);
    }
    *(half8*)&feats[(size_t)orig*32 + q*8] = hv;
}

// ---------------------------------------------------------------------------
// Round-4 unsorted gather (tier-2 fallback).
// ---------------------------------------------------------------------------
__global__ __launch_bounds__(256, 4) void ngp_gather_lin(
    const float* __restrict__ xin, const unsigned int* __restrict__ tabu,
    _Float16* __restrict__ feats,
    int4 ra, int4 rb, int4 rc, int4 rd,
    int4 oa, int4 ob, int4 oc, int4 od)
{
    const int tid = blockIdx.x * 256 + threadIdx.x;
    const int p = tid >> 2;
    const int q = tid & 3;

    const float px = (xin[3*p+0] + 1.0f) * 0.5f;
    const float py = (xin[3*p+1] + 1.0f) * 0.5f;
    const float pz = (xin[3*p+2] + 1.0f) * 0.5f;

    const int4 rv = (q == 0) ? ra : (q == 1) ? rb : (q == 2) ? rc : rd;
    const int4 ov = (q == 0) ? oa : (q == 1) ? ob : (q == 2) ? oc : od;

    uint2a4 P[16];
    float fx[4], fy[4], fz[4];
    #pragma unroll
    for (int j = 0; j < 4; ++j) {
        const int R   = (j == 0) ? rv.x : (j == 1) ? rv.y : (j == 2) ? rv.z : rv.w;
        const int off = (j == 0) ? ov.x : (j == 1) ? ov.y : (j == 2) ? ov.z : ov.w;
        const float Rf = (float)R;
        const float gx = px*Rf, gy = py*Rf, gz = pz*Rf;
        int x0 = (int)floorf(gx); x0 = x0 < 0 ? 0 : (x0 > R-1 ? R-1 : x0);
        int y0 = (int)floorf(gy); y0 = y0 < 0 ? 0 : (y0 > R-1 ? R-1 : y0);
        int z0 = (int)floorf(gz); z0 = z0 < 0 ? 0 : (z0 > R-1 ? R-1 : z0);
        fx[j] = gx - (float)x0; fy[j] = gy - (float)y0; fz[j] = gz - (float)z0;
        const int s1 = R + 1, s2 = s1 * s1;
        const unsigned int* tab = tabu + off;
        const int b = x0 + y0*s1 + z0*s2;
        P[4*j+0] = *(const uint2a4*)(tab + b);
        P[4*j+1] = *(const uint2a4*)(tab + b + s1);
        P[4*j+2] = *(const uint2a4*)(tab + b + s2);
        P[4*j+3] = *(const uint2a4*)(tab + b + s1 + s2);
    }
    half8 hv;
    #pragma unroll
    for (int j = 0; j < 4; ++j) {
        const float2 c000 = unpack_h2(P[4*j+0].x), c100 = unpack_h2(P[4*j+0].y);
        const float2 c010 = unpack_h2(P[4*j+1].x), c110 = unpack_h2(P[4*j+1].y);
        const float2 c001 = unpack_h2(P[4*j+2].x), c101 = unpack_h2(P[4*j+2].y);
        const float2 c011 = unpack_h2(P[4*j+3].x), c111 = unpack_h2(P[4*j+3].y);
        const float fxj = fx[j], fyj = fy[j], fzj = fz[j];
        const float a00x = fmaf(fxj, c100.x - c000.x, c000.x);
        const float a00y = fmaf(fxj, c100.y - c000.y, c000.y);
        const float a10x = fmaf(fxj, c110.x - c010.x, c010.x);
        const float a10y = fmaf(fxj, c110.y - c010.y, c010.y);
        const float a01x = fmaf(fxj, c101.x - c001.x, c001.x);
        const float a01y = fmaf(fxj, c101.y - c001.y, c001.y);
        const float a11x = fmaf(fxj, c111.x - c011.x, c011.x);
        const float a11y = fmaf(fxj, c111.y - c011.y, c011.y);
        const float b0x = fmaf(fyj, a10x - a00x, a00x);
        const float b1x = fmaf(fyj, a11x - a01x, a01x);
        const float b0y = fmaf(fyj, a10y - a00y, a00y);
        const float b1y = fmaf(fyj, a11y - a01y, a01y);
        hv[2*j+0] = (_Float16)fmaf(fzj, b1x - b0x, b0x);
        hv[2*j+1] = (_Float16)fmaf(fzj, b1y - b0y, b0y);
    }
    *(half8*)&feats[(size_t)p*32 + q*8] = hv;
}

// ---------------------------------------------------------------------------
// MLP kernel. 4 waves/block, 32 points/wave (wave-private LDS, no
// __syncthreads). Layers computed as Y^T = W^T @ X^T.
// ---------------------------------------------------------------------------
__global__ __launch_bounds__(256) void ngp_mlp(
    const float* __restrict__ din, const _Float16* __restrict__ feats,
    const half8* __restrict__ wfrag, float* __restrict__ out)
{
    __shared__ __align__(16) _Float16 smM[4][32][72];  // H / c1 / c2
    __shared__ __align__(16) _Float16 smG[4][32][24];  // geo feats (hd 16-31)

    const int tid  = threadIdx.x;
    const int w    = tid >> 6, lane = tid & 63;
    const int gbase = (blockIdx.x * 4 + w) * 32;

    const int n = lane & 15, g = lane >> 4;
    const floatx4 zz = {0.f, 0.f, 0.f, 0.f};

    auto storeQ = [&](int pt, int mt, floatx4 a) {
        half4 hv;
        hv[0] = (_Float16)fmaxf(a[0], 0.f); hv[1] = (_Float16)fmaxf(a[1], 0.f);
        hv[2] = (_Float16)fmaxf(a[2], 0.f); hv[3] = (_Float16)fmaxf(a[3], 0.f);
        *(half4*)&smM[w][pt][16*mt + 4*g] = hv;
    };

    // S0: feats[32] @ ws0 -> H[64], relu
    {
        const half8 A0 = wfrag[0*64+lane], A1 = wfrag[1*64+lane];
        const half8 A2 = wfrag[2*64+lane], A3 = wfrag[3*64+lane];
        #pragma unroll
        for (int nt = 0; nt < 2; ++nt) {
            const int pt = nt*16 + n;
            const half8 B = *(const half8*)&feats[(size_t)(gbase + pt)*32 + 8*g];
            floatx4 a0 = MFMA16x16x32(A0, B, zz, 0,0,0);
            floatx4 a1 = MFMA16x16x32(A1, B, zz, 0,0,0);
            floatx4 a2 = MFMA16x16x32(A2, B, zz, 0,0,0);
            floatx4 a3 = MFMA16x16x32(A3, B, zz, 0,0,0);
            storeQ(pt, 0, a0); storeQ(pt, 1, a1); storeQ(pt, 2, a2); storeQ(pt, 3, a3);
        }
    }
    asm volatile("" ::: "memory");

    // S1: H[64] @ ws1 -> G[16] (linear); sigma + geo out
    {
        const half8 A0 = wfrag[4*64+lane], A1 = wfrag[5*64+lane];
        #pragma unroll
        for (int nt = 0; nt < 2; ++nt) {
            const int pt = nt*16 + n;
            const half8 B0 = *(const half8*)&smM[w][pt][ 0 + 8*g];
            const half8 B1 = *(const half8*)&smM[w][pt][32 + 8*g];
            floatx4 acc = MFMA16x16x32(A0, B0, zz, 0,0,0);
            acc = MFMA16x16x32(A1, B1, acc, 0,0,0);
            if (g == 0) {
                out[gbase + pt] = fabsf(acc[0]);             // sigma = |g0|
                smG[w][pt][0]  = (_Float16)acc[1];
                smG[w][pt][1]  = (_Float16)acc[2];
                smG[w][pt][2]  = (_Float16)acc[3];
                smG[w][pt][15] = (_Float16)0.f;              // hd[31] pad
            } else {
                smG[w][pt][4*g-1] = (_Float16)acc[0];
                smG[w][pt][4*g+0] = (_Float16)acc[1];
                smG[w][pt][4*g+1] = (_Float16)acc[2];
                smG[w][pt][4*g+2] = (_Float16)acc[3];
            }
        }
    }
    asm volatile("" ::: "memory");

    // C0: hd[32] @ wc0 -> c1[64], relu
    {
        const half8 A0 = wfrag[6*64+lane], A1 = wfrag[7*64+lane];
        const half8 A2 = wfrag[8*64+lane], A3 = wfrag[9*64+lane];
        #pragma unroll
        for (int nt = 0; nt < 2; ++nt) {
            const int pt = nt*16 + n;
            half8 B;
            if (g < 2) {
                const int gpt = gbase + pt;
                const float x = din[3*gpt+0], y = din[3*gpt+1], z = din[3*gpt+2];
                const float xx = x*x, yy = y*y, zzq = z*z;
                const float xy = x*y, yz = y*z, xz = x*z;
                float s[8];
                if (g == 0) {
                    s[0] = 0.28209479177387814f;
                    s[1] = -0.48860251190291987f * y;
                    s[2] =  0.48860251190291987f * z;
                    s[3] = -0.48860251190291987f * x;
                    s[4] =  1.0925484305920792f * xy;
                    s[5] = -1.0925484305920792f * yz;
                    s[6] =  0.94617469575756f * zzq - 0.31539156525252005f;
                    s[7] = -1.0925484305920792f * xz;
                } else {
                    s[0] =  0.5462742152960396f * (xx - yy);
                    s[1] =  0.5900435899266435f * y * (yy - 3.0f*xx);
                    s[2] =  2.890611442640554f * xy * z;
                    s[3] =  0.4570457994644657f * y * (1.0f - 5.0f*zzq);
                    s[4] =  0.3731763325901154f * z * (5.0f*zzq - 3.0f);
                    s[5] =  0.4570457994644657f * x * (1.0f - 5.0f*zzq);
                    s[6] =  1.445305721320277f * z * (xx - yy);
                    s[7] =  0.5900435899266435f * x * (3.0f*yy - xx);
                }
                #pragma unroll
                for (int e = 0; e < 8; ++e) B[e] = (_Float16)s[e];
            } else {
                B = *(const half8*)&smG[w][pt][8*(g-2)];
            }
            floatx4 a0 = MFMA16x16x32(A0, B, zz, 0,0,0);
            floatx4 a1 = MFMA16x16x32(A1, B, zz, 0,0,0);
            floatx4 a2 = MFMA16x16x32(A2, B, zz, 0,0,0);
            floatx4 a3 = MFMA16x16x32(A3, B, zz, 0,0,0);
            storeQ(pt, 0, a0); storeQ(pt, 1, a1); storeQ(pt, 2, a2); storeQ(pt, 3, a3);
        }
    }
    asm volatile("" ::: "memory");

    // C1: c1[64] @ wc1 -> c2[64], relu
    {
        const half8 A0 = wfrag[10*64+lane], A1 = wfrag[11*64+lane];
        const half8 A2 = wfrag[12*64+lane], A3 = wfrag[13*64+lane];
        const half8 A4 = wfrag[14*64+lane], A5 = wfrag[15*64+lane];
        const half8 A6 = wfrag[16*64+lane], A7 = wfrag[17*64+lane];
        #pragma unroll
        for (int nt = 0; nt < 2; ++nt) {
            const int pt = nt*16 + n;
            const half8 B0 = *(const half8*)&smM[w][pt][ 0 + 8*g];
            const half8 B1 = *(const half8*)&smM[w][pt][32 + 8*g];
            floatx4 a0 = MFMA16x16x32(A0, B0, zz, 0,0,0); a0 = MFMA16x16x32(A1, B1, a0, 0,0,0);
            floatx4 a1 = MFMA16x16x32(A2, B0, zz, 0,0,0); a1 = MFMA16x16x32(A3, B1, a1, 0,0,0);
            floatx4 a2 = MFMA16x16x32(A4, B0, zz, 0,0,0); a2 = MFMA16x16x32(A5, B1, a2, 0,0,0);
            floatx4 a3 = MFMA16x16x32(A6, B0, zz, 0,0,0); a3 = MFMA16x16x32(A7, B1, a3, 0,0,0);
            storeQ(pt, 0, a0); storeQ(pt, 1, a1); storeQ(pt, 2, a2); storeQ(pt, 3, a3);
        }
    }
    asm volatile("" ::: "memory");

    // C2: c2[64] @ wc2 -> color (|.|)
    {
        const half8 A0 = wfrag[18*64+lane], A1 = wfrag[19*64+lane];
        #pragma unroll
        for (int nt = 0; nt < 2; ++nt) {
            const int pt = nt*16 + n;
            const half8 B0 = *(const half8*)&smM[w][pt][ 0 + 8*g];
            const half8 B1 = *(const half8*)&smM[w][pt][32 + 8*g];
            floatx4 acc = MFMA16x16x32(A0, B0, zz, 0,0,0);
            acc = MFMA16x16x32(A1, B1, acc, 0,0,0);
            if (g == 0) out[NPTS + gbase + pt] = fabsf(acc[0]);
        }
    }
}

extern "C" void kernel_launch(void* const* d_in, const int* in_sizes, int n_in,
                              void* d_out, int out_size, void* d_ws, size_t ws_size,
                              hipStream_t stream)
{
    const float* x   = (const float*)d_in[0];
    const float* d   = (const float*)d_in[1];
    const float* emb = (const float*)d_in[2];
    const float* ws0 = (const float*)d_in[3];
    const float* ws1 = (const float*)d_in[4];
    const float* wc0 = (const float*)d_in[5];
    const float* wc1 = (const float*)d_in[6];
    const float* wc2 = (const float*)d_in[7];
    float* out = (float*)d_out;

    // workspace layout
    const size_t OFF_WFRAG = 0;
    const size_t OFF_TABU  = 32768;
    const size_t OFF_FEATS = OFF_TABU + 8388608;          // 8 MB tables
    const size_t OFF_HIST  = OFF_FEATS + 67108864;        // 64 MB feats
    const size_t OFF_OFF   = OFF_HIST + NBUCK*4;
    const size_t OFF_XS4   = OFF_OFF + NBUCK*4;
    const size_t NEED_SORT = OFF_XS4 + (size_t)NPTS*16;
    const size_t NEED_LIN  = OFF_HIST;

    half8* wfrag        = (half8*)((char*)d_ws + OFF_WFRAG);
    unsigned int* tabu  = (unsigned int*)((char*)d_ws + OFF_TABU);
    _Float16* feats     = (_Float16*)((char*)d_ws + OFF_FEATS);
    unsigned int* hist  = (unsigned int*)((char*)d_ws + OFF_HIST);
    unsigned int* boff  = (unsigned int*)((char*)d_ws + OFF_OFF);
    float4* xs4         = (float4*)((char*)d_ws + OFF_XS4);

    // Replicate numpy's host-side RESOLUTIONS computation bit-for-bit.
    int r[16], off[16];
    const double s = std::exp(std::log(4.0) / 15.0);
    int acc = 0;
    for (int l = 0; l < 16; ++l) {
        r[l] = (int)std::floor(16.0 * std::pow(s, (double)l));
        off[l] = acc;
        acc += (r[l]+1)*(r[l]+1)*(r[l]+1);
    }
    const int4 ra = {r[0],  r[1],  r[2],  r[3]};
    const int4 rb = {r[4],  r[5],  r[6],  r[7]};
    const int4 rc = {r[8],  r[9],  r[10], r[11]};
    const int4 rd = {r[12], r[13], r[14], r[15]};
    const int4 oa = {off[0],  off[1],  off[2],  off[3]};
    const int4 ob = {off[4],  off[5],  off[6],  off[7]};
    const int4 oc = {off[8],  off[9],  off[10], off[11]};
    const int4 od = {off[12], off[13], off[14], off[15]};

    prepack_weights<<<20, 64, 0, stream>>>(ws0, ws1, wc0, wc1, wc2, wfrag);

    const int nmax = (r[15]+1)*(r[15]+1)*(r[15]+1);
    dim3 cgrid((nmax + 255) / 256, 16);

    if (ws_size >= NEED_SORT) {
        convert_tables<<<cgrid, 256, 0, stream>>>(emb, tabu, ra, rb, rc, rd, oa, ob, oc, od);
        hipMemsetAsync(hist, 0, NBUCK*4, stream);
        hist_kernel<<<NPTS/256, 256, 0, stream>>>(x, hist);
        scan_kernel<<<1, 1024, 0, stream>>>(hist, boff);
        scatter_kernel<<<NPTS/256, 256, 0, stream>>>(x, boff, xs4);
        ngp_gather_sorted<<<NPTS*4/256, 256, 0, stream>>>(xs4, tabu, feats, ra, rb, rc, rd, oa, ob, oc, od);
        ngp_mlp<<<NPTS/128, 256, 0, stream>>>(d, feats, wfrag, out);
    } else if (ws_size >= NEED_LIN) {
        convert_tables<<<cgrid, 256, 0, stream>>>(emb, tabu, ra, rb, rc, rd, oa, ob, oc, od);
        ngp_gather_lin<<<NPTS*4/256, 256, 0, stream>>>(x, tabu, feats, ra, rb, rc, rd, oa, ob, oc, od);
        ngp_mlp<<<NPTS/128, 256, 0, stream>>>(d, feats, wfrag, out);
    }
}

// Round 6
// 216.585 us; speedup vs baseline: 2.0024x; 1.2195x over previous
//
#include <hip/hip_runtime.h>
#include <cmath>

#define NPTS 1048576
#define TABLE_SZ 524288
#define NBUCK 32768   // 32^3 spatial buckets

typedef _Float16 half8 __attribute__((ext_vector_type(8)));
typedef _Float16 half4 __attribute__((ext_vector_type(4)));
typedef _Float16 h2 __attribute__((ext_vector_type(2)));
typedef float floatx4 __attribute__((ext_vector_type(4)));
typedef float float4a8 __attribute__((ext_vector_type(4), aligned(8)));
typedef unsigned int uint2a4 __attribute__((ext_vector_type(2), aligned(4)));

#define MFMA16x16x32 __builtin_amdgcn_mfma_f32_16x16x32_f16

__device__ __forceinline__ h2 as_h2(unsigned int u) {
    union { unsigned int u; h2 h; } c; c.u = u; return c.h;
}

// ---------------------------------------------------------------------------
// Pre-pack all MLP weights into f16 MFMA A-fragments (W^T as A operand).
//   lane l holds row m = l&15, k = 32*kt + (l>>4)*8 + e, e in [0,8).
// ---------------------------------------------------------------------------
__global__ void prepack_weights(const float* __restrict__ ws0,
                                const float* __restrict__ ws1,
                                const float* __restrict__ wc0,
                                const float* __restrict__ wc1,
                                const float* __restrict__ wc2,
                                half8* __restrict__ wfrag)
{
    const int f = blockIdx.x, l = threadIdx.x;
    const float* W; int Kreal, Mreal, mt, kt;
    if (f < 4)       { W = ws0; Kreal = 32; Mreal = 64; mt = f;          kt = 0;        }
    else if (f < 6)  { W = ws1; Kreal = 64; Mreal = 16; mt = 0;          kt = f - 4;    }
    else if (f < 10) { W = wc0; Kreal = 31; Mreal = 64; mt = f - 6;      kt = 0;        }
    else if (f < 18) { W = wc1; Kreal = 64; Mreal = 64; mt = (f-10)>>1;  kt = (f-10)&1; }
    else             { W = wc2; Kreal = 64; Mreal = 1;  mt = 0;          kt = f - 18;   }

    const int m  = 16*mt + (l & 15);
    const int k0 = 32*kt + (l >> 4)*8;
    half8 hv;
    #pragma unroll
    for (int e = 0; e < 8; ++e) {
        const int k = k0 + e;
        const float v = (m < Mreal && k < Kreal) ? W[k*Mreal + m] : 0.0f;
        hv[e] = (_Float16)v;
    }
    wfrag[f*64 + l] = hv;
}

// ---------------------------------------------------------------------------
// Convert ACTIVE region of each level's fp32 table to packed f16.
// blockIdx.y==16 blocks zero the histogram (folds memset into this launch).
// ---------------------------------------------------------------------------
__global__ __launch_bounds__(256) void convert_tables(
    const float* __restrict__ emb, unsigned int* __restrict__ tabu,
    unsigned int* __restrict__ hist, int zero_hist,
    int4 ra, int4 rb, int4 rc, int4 rd,
    int4 oa, int4 ob, int4 oc, int4 od)
{
    const int l = blockIdx.y;
    if (l == 16) {
        if (zero_hist) {
            const int e = blockIdx.x * 256 + threadIdx.x;
            if (e < NBUCK) hist[e] = 0u;
        }
        return;
    }
    const int q = l >> 2, j = l & 3;
    const int4 rv = (q == 0) ? ra : (q == 1) ? rb : (q == 2) ? rc : rd;
    const int4 ov = (q == 0) ? oa : (q == 1) ? ob : (q == 2) ? oc : od;
    const int R   = (j == 0) ? rv.x : (j == 1) ? rv.y : (j == 2) ? rv.z : rv.w;
    const int off = (j == 0) ? ov.x : (j == 1) ? ov.y : (j == 2) ? ov.z : ov.w;
    const int n = (R+1)*(R+1)*(R+1);
    const int e = blockIdx.x * 256 + threadIdx.x;
    if (e >= n) return;
    const float2 v = *(const float2*)(emb + (size_t)l * (TABLE_SZ*2) + 2*(size_t)e);
    union { unsigned int u; _Float16 h[2]; } c;
    c.h[0] = (_Float16)v.x; c.h[1] = (_Float16)v.y;
    tabu[off + e] = c.u;
}

// ---------------------------------------------------------------------------
// Spatial counting sort (32^3 buckets)
// ---------------------------------------------------------------------------
__device__ __forceinline__ int bucket_of(float px, float py, float pz) {
    int bx = (int)(px * 32.0f); bx = bx < 0 ? 0 : (bx > 31 ? 31 : bx);
    int by = (int)(py * 32.0f); by = by < 0 ? 0 : (by > 31 ? 31 : by);
    int bz = (int)(pz * 32.0f); bz = bz < 0 ? 0 : (bz > 31 ? 31 : bz);
    return bx | (by << 5) | (bz << 10);
}

// hist + per-point rank (the atomic's return value). One contended pass.
__global__ __launch_bounds__(256) void hist_kernel(
    const float* __restrict__ xin, unsigned int* __restrict__ hist,
    unsigned int* __restrict__ rnk)
{
    const int i = blockIdx.x * 256 + threadIdx.x;
    const float px = (xin[3*i+0] + 1.0f) * 0.5f;
    const float py = (xin[3*i+1] + 1.0f) * 0.5f;
    const float pz = (xin[3*i+2] + 1.0f) * 0.5f;
    rnk[i] = atomicAdd(&hist[bucket_of(px, py, pz)], 1u);
}

__global__ __launch_bounds__(1024) void scan_kernel(
    const unsigned int* __restrict__ hist, unsigned int* __restrict__ off)
{
    __shared__ unsigned int ssum[1024];
    const int t = threadIdx.x;
    unsigned int v[32];
    unsigned int s = 0;
    #pragma unroll
    for (int j = 0; j < 32; ++j) {
        const unsigned int h = hist[t*32 + j];
        v[j] = s; s += h;
    }
    ssum[t] = s;
    __syncthreads();
    for (int d = 1; d < 1024; d <<= 1) {
        const unsigned int add = (t >= d) ? ssum[t-d] : 0u;
        __syncthreads();
        ssum[t] += add;
        __syncthreads();
    }
    const unsigned int base = (t == 0) ? 0u : ssum[t-1];
    #pragma unroll
    for (int j = 0; j < 32; ++j) off[t*32 + j] = base + v[j];
}

// pure scatter: pos = boff[b] + rank[i], no atomics.
__global__ __launch_bounds__(256) void scatter_kernel(
    const float* __restrict__ xin, const unsigned int* __restrict__ boff,
    const unsigned int* __restrict__ rnk, float4* __restrict__ xs4)
{
    const int i = blockIdx.x * 256 + threadIdx.x;
    const float px = (xin[3*i+0] + 1.0f) * 0.5f;
    const float py = (xin[3*i+1] + 1.0f) * 0.5f;
    const float pz = (xin[3*i+2] + 1.0f) * 0.5f;
    const int b = bucket_of(px, py, pz);
    const unsigned int pos = boff[b] + rnk[i];
    xs4[pos] = make_float4(px, py, pz, __uint_as_float((unsigned int)i));
}

// ---------------------------------------------------------------------------
// Gather over SORTED points: 4 threads/point, 4 levels/thread, loads-first,
// packed-f16 trilinear lerp (no unpack/repack).
// Feats written back to ORIGINAL point index (64B contiguous per point).
// ---------------------------------------------------------------------------
__global__ __launch_bounds__(256, 4) void ngp_gather_sorted(
    const float4* __restrict__ xs4, const unsigned int* __restrict__ tabu,
    _Float16* __restrict__ feats,
    int4 ra, int4 rb, int4 rc, int4 rd,
    int4 oa, int4 ob, int4 oc, int4 od)
{
    const int tid = blockIdx.x * 256 + threadIdx.x;
    const int p = tid >> 2;            // sorted position
    const int q = tid & 3;             // level quad: levels 4q..4q+3

    const float4 xv = xs4[p];
    const float px = xv.x, py = xv.y, pz = xv.z;
    const unsigned int orig = __float_as_uint(xv.w);

    const int4 rv = (q == 0) ? ra : (q == 1) ? rb : (q == 2) ? rc : rd;
    const int4 ov = (q == 0) ? oa : (q == 1) ? ob : (q == 2) ? oc : od;

    uint2a4 P[16];
    float fx[4], fy[4], fz[4];

    #pragma unroll
    for (int j = 0; j < 4; ++j) {
        const int R   = (j == 0) ? rv.x : (j == 1) ? rv.y : (j == 2) ? rv.z : rv.w;
        const int off = (j == 0) ? ov.x : (j == 1) ? ov.y : (j == 2) ? ov.z : ov.w;
        const float Rf = (float)R;
        const float gx = px*Rf, gy = py*Rf, gz = pz*Rf;
        int x0 = (int)floorf(gx); x0 = x0 < 0 ? 0 : (x0 > R-1 ? R-1 : x0);
        int y0 = (int)floorf(gy); y0 = y0 < 0 ? 0 : (y0 > R-1 ? R-1 : y0);
        int z0 = (int)floorf(gz); z0 = z0 < 0 ? 0 : (z0 > R-1 ? R-1 : z0);
        fx[j] = gx - (float)x0; fy[j] = gy - (float)y0; fz[j] = gz - (float)z0;
        const int s1 = R + 1, s2 = s1 * s1;
        const unsigned int* tab = tabu + off;
        const int b = x0 + y0*s1 + z0*s2;
        P[4*j+0] = *(const uint2a4*)(tab + b);
        P[4*j+1] = *(const uint2a4*)(tab + b + s1);
        P[4*j+2] = *(const uint2a4*)(tab + b + s2);
        P[4*j+3] = *(const uint2a4*)(tab + b + s1 + s2);
    }

    union { half8 v; h2 h[4]; } hv;
    #pragma unroll
    for (int j = 0; j < 4; ++j) {
        const _Float16 fxh = (_Float16)fx[j];
        const _Float16 fyh = (_Float16)fy[j];
        const _Float16 fzh = (_Float16)fz[j];
        const h2 fx2 = {fxh, fxh}, fy2 = {fyh, fyh}, fz2 = {fzh, fzh};
        // each P word = packed (feat0,feat1) for one corner
        const h2 c000 = as_h2(P[4*j+0].x), c100 = as_h2(P[4*j+0].y);
        const h2 c010 = as_h2(P[4*j+1].x), c110 = as_h2(P[4*j+1].y);
        const h2 c001 = as_h2(P[4*j+2].x), c101 = as_h2(P[4*j+2].y);
        const h2 c011 = as_h2(P[4*j+3].x), c111 = as_h2(P[4*j+3].y);
        const h2 a00 = c000 + fx2 * (c100 - c000);
        const h2 a10 = c010 + fx2 * (c110 - c010);
        const h2 a01 = c001 + fx2 * (c101 - c001);
        const h2 a11 = c011 + fx2 * (c111 - c011);
        const h2 b0  = a00 + fy2 * (a10 - a00);
        const h2 b1  = a01 + fy2 * (a11 - a01);
        hv.h[j] = b0 + fz2 * (b1 - b0);
    }
    *(half8*)&feats[(size_t)orig*32 + q*8] = hv.v;
}

// ---------------------------------------------------------------------------
// Unsorted gather (tier-2 fallback, f16 tables, packed lerp).
// ---------------------------------------------------------------------------
__global__ __launch_bounds__(256, 4) void ngp_gather_lin(
    const float* __restrict__ xin, const unsigned int* __restrict__ tabu,
    _Float16* __restrict__ feats,
    int4 ra, int4 rb, int4 rc, int4 rd,
    int4 oa, int4 ob, int4 oc, int4 od)
{
    const int tid = blockIdx.x * 256 + threadIdx.x;
    const int p = tid >> 2;
    const int q = tid & 3;

    const float px = (xin[3*p+0] + 1.0f) * 0.5f;
    const float py = (xin[3*p+1] + 1.0f) * 0.5f;
    const float pz = (xin[3*p+2] + 1.0f) * 0.5f;

    const int4 rv = (q == 0) ? ra : (q == 1) ? rb : (q == 2) ? rc : rd;
    const int4 ov = (q == 0) ? oa : (q == 1) ? ob : (q == 2) ? oc : od;

    uint2a4 P[16];
    float fx[4], fy[4], fz[4];
    #pragma unroll
    for (int j = 0; j < 4; ++j) {
        const int R   = (j == 0) ? rv.x : (j == 1) ? rv.y : (j == 2) ? rv.z : rv.w;
        const int off = (j == 0) ? ov.x : (j == 1) ? ov.y : (j == 2) ? ov.z : ov.w;
        const float Rf = (float)R;
        const float gx = px*Rf, gy = py*Rf, gz = pz*Rf;
        int x0 = (int)floorf(gx); x0 = x0 < 0 ? 0 : (x0 > R-1 ? R-1 : x0);
        int y0 = (int)floorf(gy); y0 = y0 < 0 ? 0 : (y0 > R-1 ? R-1 : y0);
        int z0 = (int)floorf(gz); z0 = z0 < 0 ? 0 : (z0 > R-1 ? R-1 : z0);
        fx[j] = gx - (float)x0; fy[j] = gy - (float)y0; fz[j] = gz - (float)z0;
        const int s1 = R + 1, s2 = s1 * s1;
        const unsigned int* tab = tabu + off;
        const int b = x0 + y0*s1 + z0*s2;
        P[4*j+0] = *(const uint2a4*)(tab + b);
        P[4*j+1] = *(const uint2a4*)(tab + b + s1);
        P[4*j+2] = *(const uint2a4*)(tab + b + s2);
        P[4*j+3] = *(const uint2a4*)(tab + b + s1 + s2);
    }
    union { half8 v; h2 h[4]; } hv;
    #pragma unroll
    for (int j = 0; j < 4; ++j) {
        const _Float16 fxh = (_Float16)fx[j];
        const _Float16 fyh = (_Float16)fy[j];
        const _Float16 fzh = (_Float16)fz[j];
        const h2 fx2 = {fxh, fxh}, fy2 = {fyh, fyh}, fz2 = {fzh, fzh};
        const h2 c000 = as_h2(P[4*j+0].x), c100 = as_h2(P[4*j+0].y);
        const h2 c010 = as_h2(P[4*j+1].x), c110 = as_h2(P[4*j+1].y);
        const h2 c001 = as_h2(P[4*j+2].x), c101 = as_h2(P[4*j+2].y);
        const h2 c011 = as_h2(P[4*j+3].x), c111 = as_h2(P[4*j+3].y);
        const h2 a00 = c000 + fx2 * (c100 - c000);
        const h2 a10 = c010 + fx2 * (c110 - c010);
        const h2 a01 = c001 + fx2 * (c101 - c001);
        const h2 a11 = c011 + fx2 * (c111 - c011);
        const h2 b0  = a00 + fy2 * (a10 - a00);
        const h2 b1  = a01 + fy2 * (a11 - a01);
        hv.h[j] = b0 + fz2 * (b1 - b0);
    }
    *(half8*)&feats[(size_t)p*32 + q*8] = hv.v;
}

// ---------------------------------------------------------------------------
// MLP kernel. 4 waves/block, 32 points/wave (wave-private LDS, no
// __syncthreads). Layers computed as Y^T = W^T @ X^T.
// ---------------------------------------------------------------------------
__global__ __launch_bounds__(256) void ngp_mlp(
    const float* __restrict__ din, const _Float16* __restrict__ feats,
    const half8* __restrict__ wfrag, float* __restrict__ out)
{
    __shared__ __align__(16) _Float16 smM[4][32][72];  // H / c1 / c2
    __shared__ __align__(16) _Float16 smG[4][32][24];  // geo feats (hd 16-31)

    const int tid  = threadIdx.x;
    const int w    = tid >> 6, lane = tid & 63;
    const int gbase = (blockIdx.x * 4 + w) * 32;

    const int n = lane & 15, g = lane >> 4;
    const floatx4 zz = {0.f, 0.f, 0.f, 0.f};

    auto storeQ = [&](int pt, int mt, floatx4 a) {
        half4 hv;
        hv[0] = (_Float16)fmaxf(a[0], 0.f); hv[1] = (_Float16)fmaxf(a[1], 0.f);
        hv[2] = (_Float16)fmaxf(a[2], 0.f); hv[3] = (_Float16)fmaxf(a[3], 0.f);
        *(half4*)&smM[w][pt][16*mt + 4*g] = hv;
    };

    // S0: feats[32] @ ws0 -> H[64], relu
    {
        const half8 A0 = wfrag[0*64+lane], A1 = wfrag[1*64+lane];
        const half8 A2 = wfrag[2*64+lane], A3 = wfrag[3*64+lane];
        #pragma unroll
        for (int nt = 0; nt < 2; ++nt) {
            const int pt = nt*16 + n;
            const half8 B = *(const half8*)&feats[(size_t)(gbase + pt)*32 + 8*g];
            floatx4 a0 = MFMA16x16x32(A0, B, zz, 0,0,0);
            floatx4 a1 = MFMA16x16x32(A1, B, zz, 0,0,0);
            floatx4 a2 = MFMA16x16x32(A2, B, zz, 0,0,0);
            floatx4 a3 = MFMA16x16x32(A3, B, zz, 0,0,0);
            storeQ(pt, 0, a0); storeQ(pt, 1, a1); storeQ(pt, 2, a2); storeQ(pt, 3, a3);
        }
    }
    asm volatile("" ::: "memory");

    // S1: H[64] @ ws1 -> G[16] (linear); sigma + geo out
    {
        const half8 A0 = wfrag[4*64+lane], A1 = wfrag[5*64+lane];
        #pragma unroll
        for (int nt = 0; nt < 2; ++nt) {
            const int pt = nt*16 + n;
            const half8 B0 = *(const half8*)&smM[w][pt][ 0 + 8*g];
            const half8 B1 = *(const half8*)&smM[w][pt][32 + 8*g];
            floatx4 acc = MFMA16x16x32(A0, B0, zz, 0,0,0);
            acc = MFMA16x16x32(A1, B1, acc, 0,0,0);
            if (g == 0) {
                out[gbase + pt] = fabsf(acc[0]);             // sigma = |g0|
                smG[w][pt][0]  = (_Float16)acc[1];
                smG[w][pt][1]  = (_Float16)acc[2];
                smG[w][pt][2]  = (_Float16)acc[3];
                smG[w][pt][15] = (_Float16)0.f;              // hd[31] pad
            } else {
                smG[w][pt][4*g-1] = (_Float16)acc[0];
                smG[w][pt][4*g+0] = (_Float16)acc[1];
                smG[w][pt][4*g+1] = (_Float16)acc[2];
                smG[w][pt][4*g+2] = (_Float16)acc[3];
            }
        }
    }
    asm volatile("" ::: "memory");

    // C0: hd[32] @ wc0 -> c1[64], relu
    {
        const half8 A0 = wfrag[6*64+lane], A1 = wfrag[7*64+lane];
        const half8 A2 = wfrag[8*64+lane], A3 = wfrag[9*64+lane];
        #pragma unroll
        for (int nt = 0; nt < 2; ++nt) {
            const int pt = nt*16 + n;
            half8 B;
            if (g < 2) {
                const int gpt = gbase + pt;
                const float x = din[3*gpt+0], y = din[3*gpt+1], z = din[3*gpt+2];
                const float xx = x*x, yy = y*y, zzq = z*z;
                const float xy = x*y, yz = y*z, xz = x*z;
                float s[8];
                if (g == 0) {
                    s[0] = 0.28209479177387814f;
                    s[1] = -0.48860251190291987f * y;
                    s[2] =  0.48860251190291987f * z;
                    s[3] = -0.48860251190291987f * x;
                    s[4] =  1.0925484305920792f * xy;
                    s[5] = -1.0925484305920792f * yz;
                    s[6] =  0.94617469575756f * zzq - 0.31539156525252005f;
                    s[7] = -1.0925484305920792f * xz;
                } else {
                    s[0] =  0.5462742152960396f * (xx - yy);
                    s[1] =  0.5900435899266435f * y * (yy - 3.0f*xx);
                    s[2] =  2.890611442640554f * xy * z;
                    s[3] =  0.4570457994644657f * y * (1.0f - 5.0f*zzq);
                    s[4] =  0.3731763325901154f * z * (5.0f*zzq - 3.0f);
                    s[5] =  0.4570457994644657f * x * (1.0f - 5.0f*zzq);
                    s[6] =  1.445305721320277f * z * (xx - yy);
                    s[7] =  0.5900435899266435f * x * (3.0f*yy - xx);
                }
                #pragma unroll
                for (int e = 0; e < 8; ++e) B[e] = (_Float16)s[e];
            } else {
                B = *(const half8*)&smG[w][pt][8*(g-2)];
            }
            floatx4 a0 = MFMA16x16x32(A0, B, zz, 0,0,0);
            floatx4 a1 = MFMA16x16x32(A1, B, zz, 0,0,0);
            floatx4 a2 = MFMA16x16x32(A2, B, zz, 0,0,0);
            floatx4 a3 = MFMA16x16x32(A3, B, zz, 0,0,0);
            storeQ(pt, 0, a0); storeQ(pt, 1, a1); storeQ(pt, 2, a2); storeQ(pt, 3, a3);
        }
    }
    asm volatile("" ::: "memory");

    // C1: c1[64] @ wc1 -> c2[64], relu
    {
        const half8 A0 = wfrag[10*64+lane], A1 = wfrag[11*64+lane];
        const half8 A2 = wfrag[12*64+lane], A3 = wfrag[13*64+lane];
        const half8 A4 = wfrag[14*64+lane], A5 = wfrag[15*64+lane];
        const half8 A6 = wfrag[16*64+lane], A7 = wfrag[17*64+lane];
        #pragma unroll
        for (int nt = 0; nt < 2; ++nt) {
            const int pt = nt*16 + n;
            const half8 B0 = *(const half8*)&smM[w][pt][ 0 + 8*g];
            const half8 B1 = *(const half8*)&smM[w][pt][32 + 8*g];
            floatx4 a0 = MFMA16x16x32(A0, B0, zz, 0,0,0); a0 = MFMA16x16x32(A1, B1, a0, 0,0,0);
            floatx4 a1 = MFMA16x16x32(A2, B0, zz, 0,0,0); a1 = MFMA16x16x32(A3, B1, a1, 0,0,0);
            floatx4 a2 = MFMA16x16x32(A4, B0, zz, 0,0,0); a2 = MFMA16x16x32(A5, B1, a2, 0,0,0);
            floatx4 a3 = MFMA16x16x32(A6, B0, zz, 0,0,0); a3 = MFMA16x16x32(A7, B1, a3, 0,0,0);
            storeQ(pt, 0, a0); storeQ(pt, 1, a1); storeQ(pt, 2, a2); storeQ(pt, 3, a3);
        }
    }
    asm volatile("" ::: "memory");

    // C2: c2[64] @ wc2 -> color (|.|)
    {
        const half8 A0 = wfrag[18*64+lane], A1 = wfrag[19*64+lane];
        #pragma unroll
        for (int nt = 0; nt < 2; ++nt) {
            const int pt = nt*16 + n;
            const half8 B0 = *(const half8*)&smM[w][pt][ 0 + 8*g];
            const half8 B1 = *(const half8*)&smM[w][pt][32 + 8*g];
            floatx4 acc = MFMA16x16x32(A0, B0, zz, 0,0,0);
            acc = MFMA16x16x32(A1, B1, acc, 0,0,0);
            if (g == 0) out[NPTS + gbase + pt] = fabsf(acc[0]);
        }
    }
}

extern "C" void kernel_launch(void* const* d_in, const int* in_sizes, int n_in,
                              void* d_out, int out_size, void* d_ws, size_t ws_size,
                              hipStream_t stream)
{
    const float* x   = (const float*)d_in[0];
    const float* d   = (const float*)d_in[1];
    const float* emb = (const float*)d_in[2];
    const float* ws0 = (const float*)d_in[3];
    const float* ws1 = (const float*)d_in[4];
    const float* wc0 = (const float*)d_in[5];
    const float* wc1 = (const float*)d_in[6];
    const float* wc2 = (const float*)d_in[7];
    float* out = (float*)d_out;

    // workspace layout
    const size_t OFF_WFRAG = 0;
    const size_t OFF_TABU  = 32768;
    const size_t OFF_FEATS = OFF_TABU + 8388608;          // 8 MB tables
    const size_t OFF_HIST  = OFF_FEATS + 67108864;        // 64 MB feats
    const size_t OFF_OFF   = OFF_HIST + NBUCK*4;
    const size_t OFF_XS4   = OFF_OFF + NBUCK*4;
    const size_t OFF_RNK   = OFF_XS4 + (size_t)NPTS*16;
    const size_t NEED_SORT = OFF_RNK + (size_t)NPTS*4;
    const size_t NEED_LIN  = OFF_HIST;

    half8* wfrag        = (half8*)((char*)d_ws + OFF_WFRAG);
    unsigned int* tabu  = (unsigned int*)((char*)d_ws + OFF_TABU);
    _Float16* feats     = (_Float16*)((char*)d_ws + OFF_FEATS);
    unsigned int* hist  = (unsigned int*)((char*)d_ws + OFF_HIST);
    unsigned int* boff  = (unsigned int*)((char*)d_ws + OFF_OFF);
    float4* xs4         = (float4*)((char*)d_ws + OFF_XS4);
    unsigned int* rnk   = (unsigned int*)((char*)d_ws + OFF_RNK);

    // Replicate numpy's host-side RESOLUTIONS computation bit-for-bit.
    int r[16], off[16];
    const double s = std::exp(std::log(4.0) / 15.0);
    int acc = 0;
    for (int l = 0; l < 16; ++l) {
        r[l] = (int)std::floor(16.0 * std::pow(s, (double)l));
        off[l] = acc;
        acc += (r[l]+1)*(r[l]+1)*(r[l]+1);
    }
    const int4 ra = {r[0],  r[1],  r[2],  r[3]};
    const int4 rb = {r[4],  r[5],  r[6],  r[7]};
    const int4 rc = {r[8],  r[9],  r[10], r[11]};
    const int4 rd = {r[12], r[13], r[14], r[15]};
    const int4 oa = {off[0],  off[1],  off[2],  off[3]};
    const int4 ob = {off[4],  off[5],  off[6],  off[7]};
    const int4 oc = {off[8],  off[9],  off[10], off[11]};
    const int4 od = {off[12], off[13], off[14], off[15]};

    prepack_weights<<<20, 64, 0, stream>>>(ws0, ws1, wc0, wc1, wc2, wfrag);

    const int nmax = (r[15]+1)*(r[15]+1)*(r[15]+1);
    dim3 cgrid((nmax + 255) / 256, 17);   // y==16: hist zero

    if (ws_size >= NEED_SORT) {
        convert_tables<<<cgrid, 256, 0, stream>>>(emb, tabu, hist, 1, ra, rb, rc, rd, oa, ob, oc, od);
        hist_kernel<<<NPTS/256, 256, 0, stream>>>(x, hist, rnk);
        scan_kernel<<<1, 1024, 0, stream>>>(hist, boff);
        scatter_kernel<<<NPTS/256, 256, 0, stream>>>(x, boff, rnk, xs4);
        ngp_gather_sorted<<<NPTS*4/256, 256, 0, stream>>>(xs4, tabu, feats, ra, rb, rc, rd, oa, ob, oc, od);
        ngp_mlp<<<NPTS/128, 256, 0, stream>>>(d, feats, wfrag, out);
    } else if (ws_size >= NEED_LIN) {
        convert_tables<<<cgrid, 256, 0, stream>>>(emb, tabu, hist, 0, ra, rb, rc, rd, oa, ob, oc, od);
        ngp_gather_lin<<<NPTS*4/256, 256, 0, stream>>>(x, tabu, feats, ra, rb, rc, rd, oa, ob, oc, od);
        ngp_mlp<<<NPTS/128, 256, 0, stream>>>(d, feats, wfrag, out);
    }
}

// Round 7
// 192.324 us; speedup vs baseline: 2.2550x; 1.1261x over previous
//
#include <hip/hip_runtime.h>
#include <cmath>

#define NPTS 1048576
#define TABLE_SZ 524288
#define NBUCK 32768   // 32^3 spatial buckets

typedef _Float16 half8 __attribute__((ext_vector_type(8)));
typedef _Float16 half4 __attribute__((ext_vector_type(4)));
typedef _Float16 h2 __attribute__((ext_vector_type(2)));
typedef float floatx4 __attribute__((ext_vector_type(4)));
typedef unsigned int uint2a4 __attribute__((ext_vector_type(2), aligned(4)));

#define MFMA16x16x32 __builtin_amdgcn_mfma_f32_16x16x32_f16

__device__ __forceinline__ h2 as_h2(unsigned int u) {
    union { unsigned int u; h2 h; } c; c.u = u; return c.h;
}

// ---------------------------------------------------------------------------
// Pre-pack all MLP weights into f16 MFMA A-fragments (W^T as A operand).
//   lane l holds row m = l&15, k = 32*kt + (l>>4)*8 + e, e in [0,8).
// ---------------------------------------------------------------------------
__global__ void prepack_weights(const float* __restrict__ ws0,
                                const float* __restrict__ ws1,
                                const float* __restrict__ wc0,
                                const float* __restrict__ wc1,
                                const float* __restrict__ wc2,
                                half8* __restrict__ wfrag)
{
    const int f = blockIdx.x, l = threadIdx.x;
    const float* W; int Kreal, Mreal, mt, kt;
    if (f < 4)       { W = ws0; Kreal = 32; Mreal = 64; mt = f;          kt = 0;        }
    else if (f < 6)  { W = ws1; Kreal = 64; Mreal = 16; mt = 0;          kt = f - 4;    }
    else if (f < 10) { W = wc0; Kreal = 31; Mreal = 64; mt = f - 6;      kt = 0;        }
    else if (f < 18) { W = wc1; Kreal = 64; Mreal = 64; mt = (f-10)>>1;  kt = (f-10)&1; }
    else             { W = wc2; Kreal = 64; Mreal = 1;  mt = 0;          kt = f - 18;   }

    const int m  = 16*mt + (l & 15);
    const int k0 = 32*kt + (l >> 4)*8;
    half8 hv;
    #pragma unroll
    for (int e = 0; e < 8; ++e) {
        const int k = k0 + e;
        const float v = (m < Mreal && k < Kreal) ? W[k*Mreal + m] : 0.0f;
        hv[e] = (_Float16)v;
    }
    wfrag[f*64 + l] = hv;
}

// ---------------------------------------------------------------------------
// Convert ACTIVE region of each level's fp32 table to packed f16.
// blockIdx.y==16 blocks zero the histogram (folds memset into this launch).
// ---------------------------------------------------------------------------
__global__ __launch_bounds__(256) void convert_tables(
    const float* __restrict__ emb, unsigned int* __restrict__ tabu,
    unsigned int* __restrict__ hist, int zero_hist,
    int4 ra, int4 rb, int4 rc, int4 rd,
    int4 oa, int4 ob, int4 oc, int4 od)
{
    const int l = blockIdx.y;
    if (l == 16) {
        if (zero_hist) {
            const int e = blockIdx.x * 256 + threadIdx.x;
            if (e < NBUCK) hist[e] = 0u;
        }
        return;
    }
    const int q = l >> 2, j = l & 3;
    const int4 rv = (q == 0) ? ra : (q == 1) ? rb : (q == 2) ? rc : rd;
    const int4 ov = (q == 0) ? oa : (q == 1) ? ob : (q == 2) ? oc : od;
    const int R   = (j == 0) ? rv.x : (j == 1) ? rv.y : (j == 2) ? rv.z : rv.w;
    const int off = (j == 0) ? ov.x : (j == 1) ? ov.y : (j == 2) ? ov.z : ov.w;
    const int n = (R+1)*(R+1)*(R+1);
    const int e = blockIdx.x * 256 + threadIdx.x;
    if (e >= n) return;
    const float2 v = *(const float2*)(emb + (size_t)l * (TABLE_SZ*2) + 2*(size_t)e);
    union { unsigned int u; _Float16 h[2]; } c;
    c.h[0] = (_Float16)v.x; c.h[1] = (_Float16)v.y;
    tabu[off + e] = c.u;
}

// ---------------------------------------------------------------------------
// Spatial counting sort (32^3 buckets)
// ---------------------------------------------------------------------------
__device__ __forceinline__ int bucket_of(float px, float py, float pz) {
    int bx = (int)(px * 32.0f); bx = bx < 0 ? 0 : (bx > 31 ? 31 : bx);
    int by = (int)(py * 32.0f); by = by < 0 ? 0 : (by > 31 ? 31 : by);
    int bz = (int)(pz * 32.0f); bz = bz < 0 ? 0 : (bz > 31 ? 31 : bz);
    return bx | (by << 5) | (bz << 10);
}

// hist + per-point rank (the atomic's return value). One contended pass.
__global__ __launch_bounds__(256) void hist_kernel(
    const float* __restrict__ xin, unsigned int* __restrict__ hist,
    unsigned int* __restrict__ rnk)
{
    const int i = blockIdx.x * 256 + threadIdx.x;
    const float px = (xin[3*i+0] + 1.0f) * 0.5f;
    const float py = (xin[3*i+1] + 1.0f) * 0.5f;
    const float pz = (xin[3*i+2] + 1.0f) * 0.5f;
    rnk[i] = atomicAdd(&hist[bucket_of(px, py, pz)], 1u);
}

__global__ __launch_bounds__(1024) void scan_kernel(
    const unsigned int* __restrict__ hist, unsigned int* __restrict__ off)
{
    __shared__ unsigned int ssum[1024];
    const int t = threadIdx.x;
    unsigned int v[32];
    unsigned int s = 0;
    #pragma unroll
    for (int j = 0; j < 32; ++j) {
        const unsigned int h = hist[t*32 + j];
        v[j] = s; s += h;
    }
    ssum[t] = s;
    __syncthreads();
    for (int d = 1; d < 1024; d <<= 1) {
        const unsigned int add = (t >= d) ? ssum[t-d] : 0u;
        __syncthreads();
        ssum[t] += add;
        __syncthreads();
    }
    const unsigned int base = (t == 0) ? 0u : ssum[t-1];
    #pragma unroll
    for (int j = 0; j < 32; ++j) off[t*32 + j] = base + v[j];
}

// pure scatter: pos = boff[b] + rank[i], no atomics.
__global__ __launch_bounds__(256) void scatter_kernel(
    const float* __restrict__ xin, const unsigned int* __restrict__ boff,
    const unsigned int* __restrict__ rnk, float4* __restrict__ xs4)
{
    const int i = blockIdx.x * 256 + threadIdx.x;
    const float px = (xin[3*i+0] + 1.0f) * 0.5f;
    const float py = (xin[3*i+1] + 1.0f) * 0.5f;
    const float pz = (xin[3*i+2] + 1.0f) * 0.5f;
    const int b = bucket_of(px, py, pz);
    const unsigned int pos = boff[b] + rnk[i];
    xs4[pos] = make_float4(px, py, pz, __uint_as_float((unsigned int)i));
}

// ---------------------------------------------------------------------------
// Gather over SORTED points, LEVEL-MAJOR: q = blockIdx.y (level quad), every
// wave-load's 64 lanes hit the SAME level with 64 consecutive sorted points
// -> minimal distinct cache lines per instruction. Feats stored SoA in
// SORTED order: feats4[q][p] = half8 (levels 4q..4q+3), wave-write = 1KB
// fully contiguous.
// ---------------------------------------------------------------------------
__global__ __launch_bounds__(256, 4) void ngp_gather_sorted(
    const float4* __restrict__ xs4, const unsigned int* __restrict__ tabu,
    _Float16* __restrict__ feats,
    int4 ra, int4 rb, int4 rc, int4 rd,
    int4 oa, int4 ob, int4 oc, int4 od)
{
    const int p = blockIdx.x * 256 + threadIdx.x;   // sorted position
    const int q = blockIdx.y;                       // level quad (wave-uniform)

    const float4 xv = xs4[p];
    const float px = xv.x, py = xv.y, pz = xv.z;

    const int4 rv = (q == 0) ? ra : (q == 1) ? rb : (q == 2) ? rc : rd;
    const int4 ov = (q == 0) ? oa : (q == 1) ? ob : (q == 2) ? oc : od;

    uint2a4 P[16];
    float fx[4], fy[4], fz[4];

    #pragma unroll
    for (int j = 0; j < 4; ++j) {
        const int R   = (j == 0) ? rv.x : (j == 1) ? rv.y : (j == 2) ? rv.z : rv.w;
        const int off = (j == 0) ? ov.x : (j == 1) ? ov.y : (j == 2) ? ov.z : ov.w;
        const float Rf = (float)R;
        const float gx = px*Rf, gy = py*Rf, gz = pz*Rf;
        int x0 = (int)floorf(gx); x0 = x0 < 0 ? 0 : (x0 > R-1 ? R-1 : x0);
        int y0 = (int)floorf(gy); y0 = y0 < 0 ? 0 : (y0 > R-1 ? R-1 : y0);
        int z0 = (int)floorf(gz); z0 = z0 < 0 ? 0 : (z0 > R-1 ? R-1 : z0);
        fx[j] = gx - (float)x0; fy[j] = gy - (float)y0; fz[j] = gz - (float)z0;
        const int s1 = R + 1, s2 = s1 * s1;
        const unsigned int* tab = tabu + off;
        const int b = x0 + y0*s1 + z0*s2;
        P[4*j+0] = *(const uint2a4*)(tab + b);
        P[4*j+1] = *(const uint2a4*)(tab + b + s1);
        P[4*j+2] = *(const uint2a4*)(tab + b + s2);
        P[4*j+3] = *(const uint2a4*)(tab + b + s1 + s2);
    }

    union { half8 v; h2 h[4]; } hv;
    #pragma unroll
    for (int j = 0; j < 4; ++j) {
        const _Float16 fxh = (_Float16)fx[j];
        const _Float16 fyh = (_Float16)fy[j];
        const _Float16 fzh = (_Float16)fz[j];
        const h2 fx2 = {fxh, fxh}, fy2 = {fyh, fyh}, fz2 = {fzh, fzh};
        const h2 c000 = as_h2(P[4*j+0].x), c100 = as_h2(P[4*j+0].y);
        const h2 c010 = as_h2(P[4*j+1].x), c110 = as_h2(P[4*j+1].y);
        const h2 c001 = as_h2(P[4*j+2].x), c101 = as_h2(P[4*j+2].y);
        const h2 c011 = as_h2(P[4*j+3].x), c111 = as_h2(P[4*j+3].y);
        const h2 a00 = c000 + fx2 * (c100 - c000);
        const h2 a10 = c010 + fx2 * (c110 - c010);
        const h2 a01 = c001 + fx2 * (c101 - c001);
        const h2 a11 = c011 + fx2 * (c111 - c011);
        const h2 b0  = a00 + fy2 * (a10 - a00);
        const h2 b1  = a01 + fy2 * (a11 - a01);
        hv.h[j] = b0 + fz2 * (b1 - b0);
    }
    *(half8*)&feats[((size_t)q * NPTS + p) * 8] = hv.v;
}

// ---------------------------------------------------------------------------
// Unsorted gather (tier-2 fallback, f16 tables, AoS feats in orig order).
// ---------------------------------------------------------------------------
__global__ __launch_bounds__(256, 4) void ngp_gather_lin(
    const float* __restrict__ xin, const unsigned int* __restrict__ tabu,
    _Float16* __restrict__ feats,
    int4 ra, int4 rb, int4 rc, int4 rd,
    int4 oa, int4 ob, int4 oc, int4 od)
{
    const int tid = blockIdx.x * 256 + threadIdx.x;
    const int p = tid >> 2;
    const int q = tid & 3;

    const float px = (xin[3*p+0] + 1.0f) * 0.5f;
    const float py = (xin[3*p+1] + 1.0f) * 0.5f;
    const float pz = (xin[3*p+2] + 1.0f) * 0.5f;

    const int4 rv = (q == 0) ? ra : (q == 1) ? rb : (q == 2) ? rc : rd;
    const int4 ov = (q == 0) ? oa : (q == 1) ? ob : (q == 2) ? oc : od;

    uint2a4 P[16];
    float fx[4], fy[4], fz[4];
    #pragma unroll
    for (int j = 0; j < 4; ++j) {
        const int R   = (j == 0) ? rv.x : (j == 1) ? rv.y : (j == 2) ? rv.z : rv.w;
        const int off = (j == 0) ? ov.x : (j == 1) ? ov.y : (j == 2) ? ov.z : ov.w;
        const float Rf = (float)R;
        const float gx = px*Rf, gy = py*Rf, gz = pz*Rf;
        int x0 = (int)floorf(gx); x0 = x0 < 0 ? 0 : (x0 > R-1 ? R-1 : x0);
        int y0 = (int)floorf(gy); y0 = y0 < 0 ? 0 : (y0 > R-1 ? R-1 : y0);
        int z0 = (int)floorf(gz); z0 = z0 < 0 ? 0 : (z0 > R-1 ? R-1 : z0);
        fx[j] = gx - (float)x0; fy[j] = gy - (float)y0; fz[j] = gz - (float)z0;
        const int s1 = R + 1, s2 = s1 * s1;
        const unsigned int* tab = tabu + off;
        const int b = x0 + y0*s1 + z0*s2;
        P[4*j+0] = *(const uint2a4*)(tab + b);
        P[4*j+1] = *(const uint2a4*)(tab + b + s1);
        P[4*j+2] = *(const uint2a4*)(tab + b + s2);
        P[4*j+3] = *(const uint2a4*)(tab + b + s1 + s2);
    }
    union { half8 v; h2 h[4]; } hv;
    #pragma unroll
    for (int j = 0; j < 4; ++j) {
        const _Float16 fxh = (_Float16)fx[j];
        const _Float16 fyh = (_Float16)fy[j];
        const _Float16 fzh = (_Float16)fz[j];
        const h2 fx2 = {fxh, fxh}, fy2 = {fyh, fyh}, fz2 = {fzh, fzh};
        const h2 c000 = as_h2(P[4*j+0].x), c100 = as_h2(P[4*j+0].y);
        const h2 c010 = as_h2(P[4*j+1].x), c110 = as_h2(P[4*j+1].y);
        const h2 c001 = as_h2(P[4*j+2].x), c101 = as_h2(P[4*j+2].y);
        const h2 c011 = as_h2(P[4*j+3].x), c111 = as_h2(P[4*j+3].y);
        const h2 a00 = c000 + fx2 * (c100 - c000);
        const h2 a10 = c010 + fx2 * (c110 - c010);
        const h2 a01 = c001 + fx2 * (c101 - c001);
        const h2 a11 = c011 + fx2 * (c111 - c011);
        const h2 b0  = a00 + fy2 * (a10 - a00);
        const h2 b1  = a01 + fy2 * (a11 - a01);
        hv.h[j] = b0 + fz2 * (b1 - b0);
    }
    *(half8*)&feats[(size_t)p*32 + q*8] = hv.v;
}

// ---------------------------------------------------------------------------
// MLP kernel. 4 waves/block, 32 points/wave (wave-private LDS, no
// __syncthreads). SORTED=1: consumes sorted positions, B from SoA feats,
// din/out accessed through orig = xs4[pos].w.
// ---------------------------------------------------------------------------
template<int SORTED>
__global__ __launch_bounds__(256) void ngp_mlp(
    const float* __restrict__ din, const _Float16* __restrict__ feats,
    const float4* __restrict__ xs4,
    const half8* __restrict__ wfrag, float* __restrict__ out)
{
    __shared__ __align__(16) _Float16 smM[4][32][72];  // H / c1 / c2
    __shared__ __align__(16) _Float16 smG[4][32][24];  // geo feats (hd 16-31)

    const int tid  = threadIdx.x;
    const int w    = tid >> 6, lane = tid & 63;
    const int gbase = (blockIdx.x * 4 + w) * 32;

    const int n = lane & 15, g = lane >> 4;
    const floatx4 zz = {0.f, 0.f, 0.f, 0.f};

    // original point index for this lane's two points (pt = nt*16 + n)
    unsigned int orig0, orig1;
    if (SORTED) {
        orig0 = __float_as_uint(xs4[gbase + n].w);
        orig1 = __float_as_uint(xs4[gbase + 16 + n].w);
    } else {
        orig0 = gbase + n;
        orig1 = gbase + 16 + n;
    }

    auto storeQ = [&](int pt, int mt, floatx4 a) {
        half4 hv;
        hv[0] = (_Float16)fmaxf(a[0], 0.f); hv[1] = (_Float16)fmaxf(a[1], 0.f);
        hv[2] = (_Float16)fmaxf(a[2], 0.f); hv[3] = (_Float16)fmaxf(a[3], 0.f);
        *(half4*)&smM[w][pt][16*mt + 4*g] = hv;
    };

    // S0: feats[32] @ ws0 -> H[64], relu
    {
        const half8 A0 = wfrag[0*64+lane], A1 = wfrag[1*64+lane];
        const half8 A2 = wfrag[2*64+lane], A3 = wfrag[3*64+lane];
        #pragma unroll
        for (int nt = 0; nt < 2; ++nt) {
            const int pt = nt*16 + n;
            half8 B;
            if (SORTED)
                B = *(const half8*)&feats[((size_t)g * NPTS + (gbase + pt)) * 8];
            else
                B = *(const half8*)&feats[(size_t)(gbase + pt)*32 + 8*g];
            floatx4 a0 = MFMA16x16x32(A0, B, zz, 0,0,0);
            floatx4 a1 = MFMA16x16x32(A1, B, zz, 0,0,0);
            floatx4 a2 = MFMA16x16x32(A2, B, zz, 0,0,0);
            floatx4 a3 = MFMA16x16x32(A3, B, zz, 0,0,0);
            storeQ(pt, 0, a0); storeQ(pt, 1, a1); storeQ(pt, 2, a2); storeQ(pt, 3, a3);
        }
    }
    asm volatile("" ::: "memory");

    // S1: H[64] @ ws1 -> G[16] (linear); sigma + geo out
    {
        const half8 A0 = wfrag[4*64+lane], A1 = wfrag[5*64+lane];
        #pragma unroll
        for (int nt = 0; nt < 2; ++nt) {
            const int pt = nt*16 + n;
            const half8 B0 = *(const half8*)&smM[w][pt][ 0 + 8*g];
            const half8 B1 = *(const half8*)&smM[w][pt][32 + 8*g];
            floatx4 acc = MFMA16x16x32(A0, B0, zz, 0,0,0);
            acc = MFMA16x16x32(A1, B1, acc, 0,0,0);
            if (g == 0) {
                out[nt ? orig1 : orig0] = fabsf(acc[0]);     // sigma = |g0|
                smG[w][pt][0]  = (_Float16)acc[1];
                smG[w][pt][1]  = (_Float16)acc[2];
                smG[w][pt][2]  = (_Float16)acc[3];
                smG[w][pt][15] = (_Float16)0.f;              // hd[31] pad
            } else {
                smG[w][pt][4*g-1] = (_Float16)acc[0];
                smG[w][pt][4*g+0] = (_Float16)acc[1];
                smG[w][pt][4*g+1] = (_Float16)acc[2];
                smG[w][pt][4*g+2] = (_Float16)acc[3];
            }
        }
    }
    asm volatile("" ::: "memory");

    // C0: hd[32] @ wc0 -> c1[64], relu
    {
        const half8 A0 = wfrag[6*64+lane], A1 = wfrag[7*64+lane];
        const half8 A2 = wfrag[8*64+lane], A3 = wfrag[9*64+lane];
        #pragma unroll
        for (int nt = 0; nt < 2; ++nt) {
            const int pt = nt*16 + n;
            half8 B;
            if (g < 2) {
                const unsigned int gpt = nt ? orig1 : orig0;
                const float x = din[3*gpt+0], y = din[3*gpt+1], z = din[3*gpt+2];
                const float xx = x*x, yy = y*y, zzq = z*z;
                const float xy = x*y, yz = y*z, xz = x*z;
                float s[8];
                if (g == 0) {
                    s[0] = 0.28209479177387814f;
                    s[1] = -0.48860251190291987f * y;
                    s[2] =  0.48860251190291987f * z;
                    s[3] = -0.48860251190291987f * x;
                    s[4] =  1.0925484305920792f * xy;
                    s[5] = -1.0925484305920792f * yz;
                    s[6] =  0.94617469575756f * zzq - 0.31539156525252005f;
                    s[7] = -1.0925484305920792f * xz;
                } else {
                    s[0] =  0.5462742152960396f * (xx - yy);
                    s[1] =  0.5900435899266435f * y * (yy - 3.0f*xx);
                    s[2] =  2.890611442640554f * xy * z;
                    s[3] =  0.4570457994644657f * y * (1.0f - 5.0f*zzq);
                    s[4] =  0.3731763325901154f * z * (5.0f*zzq - 3.0f);
                    s[5] =  0.4570457994644657f * x * (1.0f - 5.0f*zzq);
                    s[6] =  1.445305721320277f * z * (xx - yy);
                    s[7] =  0.5900435899266435f * x * (3.0f*yy - xx);
                }
                #pragma unroll
                for (int e = 0; e < 8; ++e) B[e] = (_Float16)s[e];
            } else {
                B = *(const half8*)&smG[w][pt][8*(g-2)];
            }
            floatx4 a0 = MFMA16x16x32(A0, B, zz, 0,0,0);
            floatx4 a1 = MFMA16x16x32(A1, B, zz, 0,0,0);
            floatx4 a2 = MFMA16x16x32(A2, B, zz, 0,0,0);
            floatx4 a3 = MFMA16x16x32(A3, B, zz, 0,0,0);
            storeQ(pt, 0, a0); storeQ(pt, 1, a1); storeQ(pt, 2, a2); storeQ(pt, 3, a3);
        }
    }
    asm volatile("" ::: "memory");

    // C1: c1[64] @ wc1 -> c2[64], relu
    {
        const half8 A0 = wfrag[10*64+lane], A1 = wfrag[11*64+lane];
        const half8 A2 = wfrag[12*64+lane], A3 = wfrag[13*64+lane];
        const half8 A4 = wfrag[14*64+lane], A5 = wfrag[15*64+lane];
        const half8 A6 = wfrag[16*64+lane], A7 = wfrag[17*64+lane];
        #pragma unroll
        for (int nt = 0; nt < 2; ++nt) {
            const int pt = nt*16 + n;
            const half8 B0 = *(const half8*)&smM[w][pt][ 0 + 8*g];
            const half8 B1 = *(const half8*)&smM[w][pt][32 + 8*g];
            floatx4 a0 = MFMA16x16x32(A0, B0, zz, 0,0,0); a0 = MFMA16x16x32(A1, B1, a0, 0,0,0);
            floatx4 a1 = MFMA16x16x32(A2, B0, zz, 0,0,0); a1 = MFMA16x16x32(A3, B1, a1, 0,0,0);
            floatx4 a2 = MFMA16x16x32(A4, B0, zz, 0,0,0); a2 = MFMA16x16x32(A5, B1, a2, 0,0,0);
            floatx4 a3 = MFMA16x16x32(A6, B0, zz, 0,0,0); a3 = MFMA16x16x32(A7, B1, a3, 0,0,0);
            storeQ(pt, 0, a0); storeQ(pt, 1, a1); storeQ(pt, 2, a2); storeQ(pt, 3, a3);
        }
    }
    asm volatile("" ::: "memory");

    // C2: c2[64] @ wc2 -> color (|.|)
    {
        const half8 A0 = wfrag[18*64+lane], A1 = wfrag[19*64+lane];
        #pragma unroll
        for (int nt = 0; nt < 2; ++nt) {
            const int pt = nt*16 + n;
            const half8 B0 = *(const half8*)&smM[w][pt][ 0 + 8*g];
            const half8 B1 = *(const half8*)&smM[w][pt][32 + 8*g];
            floatx4 acc = MFMA16x16x32(A0, B0, zz, 0,0,0);
            acc = MFMA16x16x32(A1, B1, acc, 0,0,0);
            if (g == 0) out[NPTS + (nt ? orig1 : orig0)] = fabsf(acc[0]);
        }
    }
}

extern "C" void kernel_launch(void* const* d_in, const int* in_sizes, int n_in,
                              void* d_out, int out_size, void* d_ws, size_t ws_size,
                              hipStream_t stream)
{
    const float* x   = (const float*)d_in[0];
    const float* d   = (const float*)d_in[1];
    const float* emb = (const float*)d_in[2];
    const float* ws0 = (const float*)d_in[3];
    const float* ws1 = (const float*)d_in[4];
    const float* wc0 = (const float*)d_in[5];
    const float* wc1 = (const float*)d_in[6];
    const float* wc2 = (const float*)d_in[7];
    float* out = (float*)d_out;

    // workspace layout
    const size_t OFF_WFRAG = 0;
    const size_t OFF_TABU  = 32768;
    const size_t OFF_FEATS = OFF_TABU + 8388608;          // 8 MB tables
    const size_t OFF_HIST  = OFF_FEATS + 67108864;        // 64 MB feats
    const size_t OFF_OFF   = OFF_HIST + NBUCK*4;
    const size_t OFF_XS4   = OFF_OFF + NBUCK*4;
    const size_t OFF_RNK   = OFF_XS4 + (size_t)NPTS*16;
    const size_t NEED_SORT = OFF_RNK + (size_t)NPTS*4;
    const size_t NEED_LIN  = OFF_HIST;

    half8* wfrag        = (half8*)((char*)d_ws + OFF_WFRAG);
    unsigned int* tabu  = (unsigned int*)((char*)d_ws + OFF_TABU);
    _Float16* feats     = (_Float16*)((char*)d_ws + OFF_FEATS);
    unsigned int* hist  = (unsigned int*)((char*)d_ws + OFF_HIST);
    unsigned int* boff  = (unsigned int*)((char*)d_ws + OFF_OFF);
    float4* xs4         = (float4*)((char*)d_ws + OFF_XS4);
    unsigned int* rnk   = (unsigned int*)((char*)d_ws + OFF_RNK);

    // Replicate numpy's host-side RESOLUTIONS computation bit-for-bit.
    int r[16], off[16];
    const double s = std::exp(std::log(4.0) / 15.0);
    int acc = 0;
    for (int l = 0; l < 16; ++l) {
        r[l] = (int)std::floor(16.0 * std::pow(s, (double)l));
        off[l] = acc;
        acc += (r[l]+1)*(r[l]+1)*(r[l]+1);
    }
    const int4 ra = {r[0],  r[1],  r[2],  r[3]};
    const int4 rb = {r[4],  r[5],  r[6],  r[7]};
    const int4 rc = {r[8],  r[9],  r[10], r[11]};
    const int4 rd = {r[12], r[13], r[14], r[15]};
    const int4 oa = {off[0],  off[1],  off[2],  off[3]};
    const int4 ob = {off[4],  off[5],  off[6],  off[7]};
    const int4 oc = {off[8],  off[9],  off[10], off[11]};
    const int4 od = {off[12], off[13], off[14], off[15]};

    prepack_weights<<<20, 64, 0, stream>>>(ws0, ws1, wc0, wc1, wc2, wfrag);

    const int nmax = (r[15]+1)*(r[15]+1)*(r[15]+1);
    dim3 cgrid((nmax + 255) / 256, 17);   // y==16: hist zero

    if (ws_size >= NEED_SORT) {
        convert_tables<<<cgrid, 256, 0, stream>>>(emb, tabu, hist, 1, ra, rb, rc, rd, oa, ob, oc, od);
        hist_kernel<<<NPTS/256, 256, 0, stream>>>(x, hist, rnk);
        scan_kernel<<<1, 1024, 0, stream>>>(hist, boff);
        scatter_kernel<<<NPTS/256, 256, 0, stream>>>(x, boff, rnk, xs4);
        dim3 ggrid(NPTS/256, 4);          // level-major: y = level quad
        ngp_gather_sorted<<<ggrid, 256, 0, stream>>>(xs4, tabu, feats, ra, rb, rc, rd, oa, ob, oc, od);
        ngp_mlp<1><<<NPTS/128, 256, 0, stream>>>(d, feats, xs4, wfrag, out);
    } else if (ws_size >= NEED_LIN) {
        convert_tables<<<cgrid, 256, 0, stream>>>(emb, tabu, hist, 0, ra, rb, rc, rd, oa, ob, oc, od);
        ngp_gather_lin<<<NPTS*4/256, 256, 0, stream>>>(x, tabu, feats, ra, rb, rc, rd, oa, ob, oc, od);
        ngp_mlp<0><<<NPTS/128, 256, 0, stream>>>(d, feats, (const float4*)nullptr, wfrag, out);
    }
}